// Round 1
// baseline (25630.667 us; speedup 1.0000x reference)
//
#include <hip/hip_runtime.h>
#include <hip/hip_bf16.h>
#include <cmath>

#define NN 2048
#define TT 256
#define DD 16
#define HH 256
#define NBLK 512

typedef __attribute__((ext_vector_type(8))) short short8;
typedef __attribute__((ext_vector_type(4))) float f32x4;

__device__ __forceinline__ float sigmoidf_(float x){ return 1.0f/(1.0f+expf(-x)); }

// async 16B/lane global->LDS (LDS dest wave-uniform base; HW adds lane*16)
__device__ __forceinline__ void glds16(const __hip_bfloat16* g, __hip_bfloat16* l){
  __builtin_amdgcn_global_load_lds(
      (const __attribute__((address_space(1))) void*)g,
      (__attribute__((address_space(3))) void*)l, 16, 0, 0);
}

// ---------------- packing ----------------
__global__ __launch_bounds__(256) void pack_w2(const float* __restrict__ W,
                                               __hip_bfloat16* __restrict__ P){
  int tid = blockIdx.x*256 + threadIdx.x;   // 1024 blocks
  int r = tid >> 8, k = tid & 255;
  float w = W[tid];
  __hip_bfloat16 h = __float2bfloat16(w);
  __hip_bfloat16 l = __float2bfloat16(w - __bfloat162float(h));
  size_t base = (size_t)r*512;
  P[base + k] = h; P[base + 256 + k] = l;
}
__global__ __launch_bounds__(256) void pack_w0(const float* __restrict__ W,
                                               __hip_bfloat16* __restrict__ P){
  int tid = blockIdx.x*256 + threadIdx.x;   // 64 blocks
  int r = tid >> 4, k = tid & 15;
  float w = W[tid];
  __hip_bfloat16 h = __float2bfloat16(w);
  __hip_bfloat16 l = __float2bfloat16(w - __bfloat162float(h));
  size_t base = (size_t)r*64;
  P[base + k] = h; P[base + 16 + k] = h; P[base + 32 + k] = l;
  P[base + 48 + k] = __float2bfloat16(0.0f);
}
__global__ __launch_bounds__(256) void pack_x(const float* __restrict__ x,
                                              __hip_bfloat16* __restrict__ Xp){
  int tid = blockIdx.x*256 + threadIdx.x;   // 2048 blocks
  const float* xr = x + (size_t)tid*16;
  __hip_bfloat16* o = Xp + (size_t)tid*64;
  for (int k=0;k<16;k++){
    float v = xr[k];
    __hip_bfloat16 h = __float2bfloat16(v);
    __hip_bfloat16 l = __float2bfloat16(v - __bfloat162float(h));
    o[k] = h; o[16+k] = l; o[32+k] = h; o[48+k] = __float2bfloat16(0.0f);
  }
}
__global__ __launch_bounds__(256) void recon_nf(const __hip_bfloat16* __restrict__ hi,
    const __hip_bfloat16* __restrict__ lo, float* __restrict__ nf){
  int tid = blockIdx.x*256 + threadIdx.x;
  nf[tid] = __bfloat162float(hi[tid]) + __bfloat162float(lo[tid]);
}

// ---------------- device-wide barrier ----------------
// Monotonic counters (never reset mid-run -> no reset race). 16 leaves x 32
// blocks, root, then a generation word. Re-zeroed per replay by bar_init.
__global__ __launch_bounds__(256) void bar_init(unsigned* __restrict__ bar){
  for (int i = threadIdx.x; i < 18*32; i += 256) bar[i] = 0u;
}

__device__ __forceinline__ void grid_sync(unsigned* bar, int t, int bid){
  // release: per-wave vmcnt drain + L2 writeback (h tiles cross XCDs; per-XCD
  // L2s are non-coherent, so this replicates the end-of-kernel flush)
  __threadfence();
  __syncthreads();
  if (threadIdx.x == 0){
    unsigned* leaf = bar + (bid & 15)*32;
    unsigned a = __hip_atomic_fetch_add(leaf, 1u, __ATOMIC_RELAXED,
                                        __HIP_MEMORY_SCOPE_AGENT);
    if (a == (unsigned)(32*(t+1) - 1)){
      unsigned ra = __hip_atomic_fetch_add(bar + 16*32, 1u, __ATOMIC_RELAXED,
                                           __HIP_MEMORY_SCOPE_AGENT);
      if (ra == (unsigned)(16*(t+1) - 1)){
        __hip_atomic_store(bar + 17*32, (unsigned)(t+1), __ATOMIC_RELEASE,
                           __HIP_MEMORY_SCOPE_AGENT);
      }
    }
    while (__hip_atomic_load(bar + 17*32, __ATOMIC_RELAXED,
                             __HIP_MEMORY_SCOPE_AGENT) < (unsigned)(t+1)){
      __builtin_amdgcn_s_sleep(2);
    }
  }
  __syncthreads();
  // acquire: invalidate L1/L2 so next step's h reads see remote writes
  __threadfence();
}

// ---------------- GEMM segment: merged-A chunks, drain pattern ----------------
__device__ __forceinline__ void mm_merged(
    const __hip_bfloat16* __restrict__ Ahi, const __hip_bfloat16* __restrict__ Alo,
    size_t lda,
    const __hip_bfloat16* __restrict__ Bhi, const __hip_bfloat16* __restrict__ Blo,
    size_t ldb, int Klen,
    int m0, int j0, int wv, int lane, int rr, int sw8, int frow,
    f32x4 (&acc)[2][4],
    __hip_bfloat16* AsH, __hip_bfloat16* AsL,
    __hip_bfloat16* BsH, __hip_bfloat16* BsL)
{
  const size_t arow = (size_t)(m0 + wv*32 + rr)*lda + sw8;
  const size_t brow = (size_t)(wv*256 + j0 + rr)*ldb + sw8;
  for (int kb=0; kb<Klen; kb+=64){
    {
      const __hip_bfloat16* AbH = Ahi + arow + kb;
      __hip_bfloat16* AdH = AsH + (wv*32)*64;
      #pragma unroll
      for (int c2=0;c2<4;c2++) glds16(AbH + (size_t)(c2*8)*lda, AdH + c2*8*64);
      const __hip_bfloat16* AbL = Alo + arow + kb;
      __hip_bfloat16* AdL = AsL + (wv*32)*64;
      #pragma unroll
      for (int c2=0;c2<4;c2++) glds16(AbL + (size_t)(c2*8)*lda, AdL + c2*8*64);
      const __hip_bfloat16* Bb1 = Bhi + brow + kb;
      __hip_bfloat16* Bd1 = BsH + (wv<<4)*64;
      glds16(Bb1, Bd1); glds16(Bb1 + (size_t)8*ldb, Bd1 + 8*64);
      const __hip_bfloat16* Bb2 = Blo + brow + kb;
      __hip_bfloat16* Bd2 = BsL + (wv<<4)*64;
      glds16(Bb2, Bd2); glds16(Bb2 + (size_t)8*ldb, Bd2 + 8*64);
    }
    __syncthreads();          // drains this chunk's loads
    #pragma unroll
    for (int w2=0; w2<2; ++w2){
      const int sl8 = ((((w2<<2) + (lane>>4)) ^ (lane&7)) << 3);
      short8 ah0 = *(const short8*)&AsH[(wv*32 +      frow)*64 + sl8];
      short8 ah1 = *(const short8*)&AsH[(wv*32 + 16 + frow)*64 + sl8];
      short8 al0 = *(const short8*)&AsL[(wv*32 +      frow)*64 + sl8];
      short8 al1 = *(const short8*)&AsL[(wv*32 + 16 + frow)*64 + sl8];
      #pragma unroll
      for (int g=0; g<4; ++g){
        short8 bh = *(const short8*)&BsH[((g<<4) + frow)*64 + sl8];
        acc[0][g] = __builtin_amdgcn_mfma_f32_16x16x32_bf16(ah0, bh, acc[0][g], 0,0,0);
        acc[1][g] = __builtin_amdgcn_mfma_f32_16x16x32_bf16(ah1, bh, acc[1][g], 0,0,0);
        acc[0][g] = __builtin_amdgcn_mfma_f32_16x16x32_bf16(al0, bh, acc[0][g], 0,0,0);
        acc[1][g] = __builtin_amdgcn_mfma_f32_16x16x32_bf16(al1, bh, acc[1][g], 0,0,0);
        short8 bl = *(const short8*)&BsL[((g<<4) + frow)*64 + sl8];
        acc[0][g] = __builtin_amdgcn_mfma_f32_16x16x32_bf16(ah0, bl, acc[0][g], 0,0,0);
        acc[1][g] = __builtin_amdgcn_mfma_f32_16x16x32_bf16(ah1, bl, acc[1][g], 0,0,0);
      }
    }
    __syncthreads();
  }
}

__device__ __forceinline__ void mm_single64(
    const __hip_bfloat16* __restrict__ A, size_t lda,
    const __hip_bfloat16* __restrict__ B, size_t ldb,
    int m0, int j0, int wv, int lane, int rr, int sw8, int frow,
    f32x4 (&acc)[2][4],
    __hip_bfloat16* As0, __hip_bfloat16* Bh0)
{
  {
    const __hip_bfloat16* Ab = A + (size_t)(m0 + wv*32 + rr)*lda + sw8;
    __hip_bfloat16* Ad = As0 + (wv*32)*64;
    #pragma unroll
    for (int c2=0;c2<4;c2++) glds16(Ab + (size_t)(c2*8)*lda, Ad + c2*8*64);
    const __hip_bfloat16* Bb1 = B + (size_t)(wv*256 + j0 + rr)*ldb + sw8;
    __hip_bfloat16* Bd1 = Bh0 + (wv<<4)*64;
    glds16(Bb1, Bd1); glds16(Bb1 + (size_t)8*ldb, Bd1 + 8*64);
  }
  __syncthreads();
  #pragma unroll
  for (int w2=0; w2<2; ++w2){
    const int sl8 = ((((w2<<2) + (lane>>4)) ^ (lane&7)) << 3);
    short8 a0 = *(const short8*)&As0[(wv*32 +      frow)*64 + sl8];
    short8 a1 = *(const short8*)&As0[(wv*32 + 16 + frow)*64 + sl8];
    #pragma unroll
    for (int g=0; g<4; ++g){
      short8 b1 = *(const short8*)&Bh0[((g<<4) + frow)*64 + sl8];
      acc[0][g] = __builtin_amdgcn_mfma_f32_16x16x32_bf16(a0, b1, acc[0][g], 0,0,0);
      acc[1][g] = __builtin_amdgcn_mfma_f32_16x16x32_bf16(a1, b1, acc[1][g], 0,0,0);
    }
  }
  __syncthreads();
}

// ---------------- persistent two-layer skewed LSTM (all 257 steps) ----------------
// Same per-step math/block mapping as the multi-launch version; the t-loop now
// lives inside the kernel with a device-wide barrier between steps. Cell state
// c stays in registers (was 8 MB/step of global traffic); biases hoisted.
// 512 blocks @ __launch_bounds__(256,2) -> 2 blocks/CU co-resident on 256 CUs.
__global__ __launch_bounds__(256, 2) void lstm2_all(
    const __hip_bfloat16* __restrict__ Xp,
    const __hip_bfloat16* __restrict__ P0ih,
    const __hip_bfloat16* __restrict__ P0hh,
    const __hip_bfloat16* __restrict__ P1ih,
    const __hip_bfloat16* __restrict__ P1hh,
    const float* __restrict__ bih0, const float* __restrict__ bhh0,
    const float* __restrict__ bih1, const float* __restrict__ bhh1,
    __hip_bfloat16* __restrict__ H0hi0, __hip_bfloat16* __restrict__ H0lo0,
    __hip_bfloat16* __restrict__ H0hi1, __hip_bfloat16* __restrict__ H0lo1,
    __hip_bfloat16* __restrict__ H1hi0, __hip_bfloat16* __restrict__ H1lo0,
    __hip_bfloat16* __restrict__ H1hi1, __hip_bfloat16* __restrict__ H1lo1,
    unsigned* __restrict__ bar)
{
  __shared__ __align__(16) __hip_bfloat16 AsH[128*64];   // 16 KB
  __shared__ __align__(16) __hip_bfloat16 AsL[128*64];   // 16 KB
  __shared__ __align__(16) __hip_bfloat16 BsH[64*64];    // 8 KB
  __shared__ __align__(16) __hip_bfloat16 BsL[64*64];    // 8 KB

  const int bid = blockIdx.x;
  const int xcd = bid & 7;
  const int slot = bid >> 3;
  const bool isL0 = xcd < 4;
  const int lg = isL0 ? xcd : (xcd - 4);
  const int jg = ((lg & 1) << 3) + (slot & 7);
  const int mg = ((lg >> 1) << 3) + (slot >> 3);
  const int m0 = mg << 7;
  const int j0 = jg << 4;
  const int lane = threadIdx.x & 63, wv = threadIdx.x >> 6;
  const int rr = lane >> 3;
  const int sw8 = (((lane & 7) ^ rr) << 3);
  const int frow = lane & 15;

  // hoisted epilogue constants
  const int j = j0 + frow;
  const float* bih = isL0 ? bih0 : bih1;
  const float* bhh = isL0 ? bhh0 : bhh1;
  const float b0 = bih[j]        + bhh[j];
  const float b1 = bih[HH + j]   + bhh[HH + j];
  const float b2 = bih[2*HH + j] + bhh[2*HH + j];
  const float b3 = bih[3*HH + j] + bhh[3*HH + j];

  float creg[2][4] = {{0.f,0.f,0.f,0.f},{0.f,0.f,0.f,0.f}};  // cell state in regs

  for (int t = 0; t <= TT; ++t){
    const int p = t & 1;
    const bool active = isL0 ? (t < TT) : (t >= 1);
    if (active){
      f32x4 acc[2][4] = {};
      // ping-pong pointer selects (ternary -> cndmask, no scratch arrays)
      const __hip_bfloat16* h0p_hi = p ? H0hi0 : H0hi1;   // H0[(t+1)&1]
      const __hip_bfloat16* h0p_lo = p ? H0lo0 : H0lo1;
      if (isL0){
        if (t != 0){
          mm_merged(h0p_hi, h0p_lo, 256, P0hh, P0hh+256, 512, 256,
                    m0, j0, wv, lane, rr, sw8, frow, acc, AsH, AsL, BsH, BsL);
        }
        mm_single64(Xp + (size_t)t*64, (size_t)TT*64, P0ih, 64,
                    m0, j0, wv, lane, rr, sw8, frow, acc, AsH, BsH);
      } else {
        mm_merged(h0p_hi, h0p_lo, 256, P1ih, P1ih+256, 512, 256,
                  m0, j0, wv, lane, rr, sw8, frow, acc, AsH, AsL, BsH, BsL);
        if (t != 1){
          const __hip_bfloat16* h1p_hi = p ? H1hi1 : H1hi0;  // H1[t&1]
          const __hip_bfloat16* h1p_lo = p ? H1lo1 : H1lo0;
          mm_merged(h1p_hi, h1p_lo, 256, P1hh, P1hh+256, 512, 256,
                    m0, j0, wv, lane, rr, sw8, frow, acc, AsH, AsL, BsH, BsL);
        }
      }
      __hip_bfloat16* ohi = isL0 ? (p ? H0hi1 : H0hi0)     // H0[t&1]
                                 : (p ? H1hi0 : H1hi1);    // H1[(t+1)&1]
      __hip_bfloat16* olo = isL0 ? (p ? H0lo1 : H0lo0)
                                 : (p ? H1lo0 : H1lo1);
      #pragma unroll
      for (int mt=0; mt<2; ++mt){
        const int mrb = m0 + wv*32 + mt*16 + ((lane>>4)<<2);
        #pragma unroll
        for (int r=0; r<4; ++r){
          const size_t mi = (size_t)(mrb + r)*HH + j;
          float gi = acc[mt][0][r] + b0;
          float gf = acc[mt][1][r] + b1;
          float gg = acc[mt][2][r] + b2;
          float go = acc[mt][3][r] + b3;
          float cn = sigmoidf_(gf)*creg[mt][r] + sigmoidf_(gi)*tanhf(gg);
          creg[mt][r] = cn;
          float hv = sigmoidf_(go)*tanhf(cn);
          __hip_bfloat16 hb = __float2bfloat16(hv);
          ohi[mi] = hb;
          olo[mi] = __float2bfloat16(hv - __bfloat162float(hb));
        }
      }
    }
    if (t < TT) grid_sync(bar, t, bid);   // no barrier needed after final step
  }
}

// ---------------- fp32 tail (unchanged, proven) ----------------
__global__ __launch_bounds__(256) void gemm_nn(
    float* __restrict__ C, const float* __restrict__ A, const float* __restrict__ B,
    int K, int lda, int ldb, int ldc, int relu)
{
  __shared__ float As_[16][68];
  __shared__ float Bs_[16][64];
  float acc[4][4] = {};
  const int tx = threadIdx.x;
  const int m0 = blockIdx.y<<6, n0 = blockIdx.x<<6;
  const int am = tx>>2, ak = (tx&3)<<2;
  const int bk = tx>>4, bn = (tx&15)<<2;
  const int mm = (tx>>4)<<2, nc = (tx&15)<<2;
  for (int kb=0; kb<K; kb+=16){
    float4 av = *reinterpret_cast<const float4*>(A + (size_t)(m0+am)*lda + kb + ak);
    As_[ak][am]=av.x; As_[ak+1][am]=av.y; As_[ak+2][am]=av.z; As_[ak+3][am]=av.w;
    *reinterpret_cast<float4*>(&Bs_[bk][bn]) =
      *reinterpret_cast<const float4*>(B + (size_t)(kb+bk)*ldb + n0 + bn);
    __syncthreads();
    #pragma unroll
    for (int k=0;k<16;k++){
      float4 a4 = *reinterpret_cast<const float4*>(&As_[k][mm]);
      float4 b4 = *reinterpret_cast<const float4*>(&Bs_[k][nc]);
      acc[0][0]=fmaf(a4.x,b4.x,acc[0][0]); acc[0][1]=fmaf(a4.x,b4.y,acc[0][1]);
      acc[0][2]=fmaf(a4.x,b4.z,acc[0][2]); acc[0][3]=fmaf(a4.x,b4.w,acc[0][3]);
      acc[1][0]=fmaf(a4.y,b4.x,acc[1][0]); acc[1][1]=fmaf(a4.y,b4.y,acc[1][1]);
      acc[1][2]=fmaf(a4.y,b4.z,acc[1][2]); acc[1][3]=fmaf(a4.y,b4.w,acc[1][3]);
      acc[2][0]=fmaf(a4.z,b4.x,acc[2][0]); acc[2][1]=fmaf(a4.z,b4.y,acc[2][1]);
      acc[2][2]=fmaf(a4.z,b4.z,acc[2][2]); acc[2][3]=fmaf(a4.z,b4.w,acc[2][3]);
      acc[3][0]=fmaf(a4.w,b4.x,acc[3][0]); acc[3][1]=fmaf(a4.w,b4.y,acc[3][1]);
      acc[3][2]=fmaf(a4.w,b4.z,acc[3][2]); acc[3][3]=fmaf(a4.w,b4.w,acc[3][3]);
    }
    __syncthreads();
  }
  #pragma unroll
  for (int r=0;r<4;r++){
    float4 v = make_float4(acc[r][0],acc[r][1],acc[r][2],acc[r][3]);
    if (relu){ v.x=fmaxf(v.x,0.f); v.y=fmaxf(v.y,0.f); v.z=fmaxf(v.z,0.f); v.w=fmaxf(v.w,0.f); }
    *reinterpret_cast<float4*>(C + (size_t)(m0+mm+r)*ldc + n0 + nc) = v;
  }
}

__global__ __launch_bounds__(256) void gemm_nt(
    float* __restrict__ C, const float* __restrict__ A, const float* __restrict__ B,
    int K, int lda, int ldb, int ldc)
{
  __shared__ float As_[16][68];
  __shared__ float Bs_[16][68];
  float acc[4][4] = {};
  const int tx = threadIdx.x;
  const int m0 = blockIdx.y<<6, n0 = blockIdx.x<<6;
  const int am = tx>>2, ak = (tx&3)<<2;
  const int mm = (tx>>4)<<2, nc = (tx&15)<<2;
  for (int kb=0; kb<K; kb+=16){
    float4 av = *reinterpret_cast<const float4*>(A + (size_t)(m0+am)*lda + kb + ak);
    As_[ak][am]=av.x; As_[ak+1][am]=av.y; As_[ak+2][am]=av.z; As_[ak+3][am]=av.w;
    float4 bv = *reinterpret_cast<const float4*>(B + (size_t)(n0+am)*ldb + kb + ak);
    Bs_[ak][am]=bv.x; Bs_[ak+1][am]=bv.y; Bs_[ak+2][am]=bv.z; Bs_[ak+3][am]=bv.w;
    __syncthreads();
    #pragma unroll
    for (int k=0;k<16;k++){
      float4 a4 = *reinterpret_cast<const float4*>(&As_[k][mm]);
      float4 b4 = *reinterpret_cast<const float4*>(&Bs_[k][nc]);
      acc[0][0]=fmaf(a4.x,b4.x,acc[0][0]); acc[0][1]=fmaf(a4.x,b4.y,acc[0][1]);
      acc[0][2]=fmaf(a4.x,b4.z,acc[0][2]); acc[0][3]=fmaf(a4.x,b4.w,acc[0][3]);
      acc[1][0]=fmaf(a4.y,b4.x,acc[1][0]); acc[1][1]=fmaf(a4.y,b4.y,acc[1][1]);
      acc[1][2]=fmaf(a4.y,b4.z,acc[1][2]); acc[1][3]=fmaf(a4.y,b4.w,acc[1][3]);
      acc[2][0]=fmaf(a4.z,b4.x,acc[2][0]); acc[2][1]=fmaf(a4.z,b4.y,acc[2][1]);
      acc[2][2]=fmaf(a4.z,b4.z,acc[2][2]); acc[2][3]=fmaf(a4.z,b4.w,acc[2][3]);
      acc[3][0]=fmaf(a4.w,b4.x,acc[3][0]); acc[3][1]=fmaf(a4.w,b4.y,acc[3][1]);
      acc[3][2]=fmaf(a4.w,b4.z,acc[3][2]); acc[3][3]=fmaf(a4.w,b4.w,acc[3][3]);
    }
    __syncthreads();
  }
  #pragma unroll
  for (int r=0;r<4;r++){
    float4 v = make_float4(acc[r][0],acc[r][1],acc[r][2],acc[r][3]);
    *reinterpret_cast<float4*>(C + (size_t)(m0+mm+r)*ldc + n0 + nc) = v;
  }
}

__global__ __launch_bounds__(256) void rowstat(const float* __restrict__ nf,
    float* __restrict__ xc, float* __restrict__ dvec)
{
  __shared__ float red[256];
  int n = blockIdx.x, tx = threadIdx.x;
  float v = nf[(size_t)n*HH + tx];
  red[tx] = v; __syncthreads();
  for (int s=128; s>0; s>>=1){ if (tx<s) red[tx]+=red[tx+s]; __syncthreads(); }
  float mean = red[0] * (1.0f/HH);
  __syncthreads();
  float d = v - mean;
  xc[(size_t)n*HH + tx] = d;
  red[tx] = d*d; __syncthreads();
  for (int s=128; s>0; s>>=1){ if (tx<s) red[tx]+=red[tx+s]; __syncthreads(); }
  if (tx==0) dvec[n] = sqrtf(red[0]);
}

__global__ __launch_bounds__(256) void rowsum(const float* __restrict__ cov,
    const float* __restrict__ dvec, float* __restrict__ dinv)
{
  __shared__ float red[256];
  int i = blockIdx.x, tx = threadIdx.x;
  float di = dvec[i];
  float s = 0.f;
  for (int jj=tx; jj<NN; jj+=256){
    float r = cov[(size_t)i*NN + jj] / (di * dvec[jj]);
    if (r != r) r = 0.f; else r = fminf(1.f, fmaxf(-1.f, r));
    s += r;
  }
  red[tx]=s; __syncthreads();
  for (int st=128; st>0; st>>=1){ if (tx<st) red[tx]+=red[tx+st]; __syncthreads(); }
  if (tx==0){
    float tot = red[0] + 1.0f;
    float p = powf(tot, -0.5f);
    if (isinf(p)) p = 0.f;
    dinv[i] = p;
  }
}

__global__ __launch_bounds__(256) void adjnorm(float* __restrict__ cov,
    const float* __restrict__ dvec, const float* __restrict__ dinv)
{
  size_t idx = (size_t)blockIdx.x*256 + threadIdx.x;
  int i = (int)(idx >> 11), jj = (int)(idx & (NN-1));
  float r = cov[idx] / (dvec[i]*dvec[jj]);
  if (r != r) r = 0.f; else r = fminf(1.f, fmaxf(-1.f, r));
  if (i==jj) r += 1.f;
  cov[idx] = dinv[i]*r*dinv[jj];
}

__global__ __launch_bounds__(128) void predk(const float* __restrict__ G2,
    const float* __restrict__ Wfc, const float* __restrict__ bfc, float* __restrict__ out)
{
  int n = blockIdx.x, tx = threadIdx.x;
  float v = G2[(size_t)n*128 + tx] * Wfc[tx];
  for (int off=32; off>0; off>>=1) v += __shfl_down(v, off);
  __shared__ float p[2];
  if ((tx&63)==0) p[tx>>6] = v;
  __syncthreads();
  if (tx==0) out[n] = p[0] + p[1] + bfc[0];
}

extern "C" void kernel_launch(void* const* d_in, const int* in_sizes, int n_in,
                              void* d_out, int out_size, void* d_ws, size_t ws_size,
                              hipStream_t stream)
{
  const float* x    = (const float*)d_in[0];
  const float* Wih0 = (const float*)d_in[1];
  const float* Whh0 = (const float*)d_in[2];
  const float* bih0 = (const float*)d_in[3];
  const float* bhh0 = (const float*)d_in[4];
  const float* Wih1 = (const float*)d_in[5];
  const float* Whh1 = (const float*)d_in[6];
  const float* bih1 = (const float*)d_in[7];
  const float* bhh1 = (const float*)d_in[8];
  const float* Wg1  = (const float*)d_in[9];
  const float* Wg2  = (const float*)d_in[10];
  const float* Wfc  = (const float*)d_in[11];
  const float* bfc  = (const float*)d_in[12];
  float* out = (float*)d_out;

  char* w = (char*)d_ws;
  auto alloc = [&](size_t bytes){ char* p = w; w += (bytes + 255) & ~(size_t)255; return p; };
  __hip_bfloat16* Xp   = (__hip_bfloat16*)alloc((size_t)NN*TT*64*2);
  __hip_bfloat16* P0hh = (__hip_bfloat16*)alloc((size_t)1024*512*2);
  __hip_bfloat16* P1ih = (__hip_bfloat16*)alloc((size_t)1024*512*2);
  __hip_bfloat16* P1hh = (__hip_bfloat16*)alloc((size_t)1024*512*2);
  __hip_bfloat16* P0ih = (__hip_bfloat16*)alloc((size_t)1024*64*2);
  __hip_bfloat16 *H0hi[2], *H0lo[2], *H1hi[2], *H1lo[2];
  for (int i=0;i<2;i++){ H0hi[i]=(__hip_bfloat16*)alloc((size_t)NN*HH*2);
                         H0lo[i]=(__hip_bfloat16*)alloc((size_t)NN*HH*2); }
  for (int i=0;i<2;i++){ H1hi[i]=(__hip_bfloat16*)alloc((size_t)NN*HH*2);
                         H1lo[i]=(__hip_bfloat16*)alloc((size_t)NN*HH*2); }
  float* nf   = (float*)alloc((size_t)NN*HH*4);
  float* xc   = (float*)alloc((size_t)NN*HH*4);
  float* cov  = (float*)alloc((size_t)NN*NN*4);
  float* t1   = (float*)alloc((size_t)NN*HH*4);
  float* G1   = (float*)alloc((size_t)NN*HH*4);
  float* t2   = (float*)alloc((size_t)NN*128*4);
  float* G2   = (float*)alloc((size_t)NN*128*4);
  float* dvec = (float*)alloc((size_t)NN*4);
  float* dinv = (float*)alloc((size_t)NN*4);
  unsigned* bar = (unsigned*)alloc(4096);

  hipLaunchKernelGGL(bar_init, dim3(1), dim3(256), 0, stream, bar);
  hipLaunchKernelGGL(pack_w2, dim3(1024), dim3(256), 0, stream, Whh0, P0hh);
  hipLaunchKernelGGL(pack_w2, dim3(1024), dim3(256), 0, stream, Wih1, P1ih);
  hipLaunchKernelGGL(pack_w2, dim3(1024), dim3(256), 0, stream, Whh1, P1hh);
  hipLaunchKernelGGL(pack_w0, dim3(64),   dim3(256), 0, stream, Wih0, P0ih);
  hipLaunchKernelGGL(pack_x,  dim3(2048), dim3(256), 0, stream, x, Xp);

  // persistent skewed recurrence: all 257 steps inside one kernel
  hipLaunchKernelGGL(lstm2_all, dim3(NBLK), dim3(256), 0, stream,
      Xp, P0ih, P0hh, P1ih, P1hh, bih0, bhh0, bih1, bhh1,
      H0hi[0], H0lo[0], H0hi[1], H0lo[1],
      H1hi[0], H1lo[0], H1hi[1], H1lo[1], bar);

  // final h1 (step 255, written at loop t=256) lives in H1[1]
  hipLaunchKernelGGL(recon_nf, dim3(2048), dim3(256), 0, stream, H1hi[1], H1lo[1], nf);

  hipLaunchKernelGGL(rowstat, dim3(NN), dim3(256), 0, stream, nf, xc, dvec);
  hipLaunchKernelGGL(gemm_nt, dim3(NN/64, NN/64), dim3(256), 0, stream,
      cov, xc, xc, HH, HH, HH, NN);
  hipLaunchKernelGGL(rowsum, dim3(NN), dim3(256), 0, stream, cov, dvec, dinv);
  hipLaunchKernelGGL(adjnorm, dim3(NN*NN/256), dim3(256), 0, stream, cov, dvec, dinv);

  hipLaunchKernelGGL(gemm_nn, dim3(HH/64, NN/64), dim3(256), 0, stream,
      t1, nf, Wg1, HH, HH, HH, HH, 0);
  hipLaunchKernelGGL(gemm_nn, dim3(HH/64, NN/64), dim3(256), 0, stream,
      G1, cov, t1, NN, NN, HH, HH, 1);
  hipLaunchKernelGGL(gemm_nn, dim3(128/64, NN/64), dim3(256), 0, stream,
      t2, G1, Wg2, HH, HH, 128, 128, 0);
  hipLaunchKernelGGL(gemm_nn, dim3(128/64, NN/64), dim3(256), 0, stream,
      G2, cov, t2, NN, NN, 128, 128, 0);
  hipLaunchKernelGGL(predk, dim3(NN), dim3(128), 0, stream, G2, Wfc, bfc, out);
}

// Round 2
// 6400.723 us; speedup vs baseline: 4.0043x; 4.0043x over previous
//
#include <hip/hip_runtime.h>
#include <hip/hip_bf16.h>
#include <cmath>

#define NN 2048
#define TT 256
#define DD 16
#define HH 256

typedef __attribute__((ext_vector_type(8))) short short8;
typedef __attribute__((ext_vector_type(4))) float f32x4;

__device__ __forceinline__ float sigmoidf_(float x){ return 1.0f/(1.0f+expf(-x)); }

__device__ __forceinline__ short8 ld8bf(const __hip_bfloat16* p){
  return *reinterpret_cast<const short8*>(p);
}

// async 16B/lane global->LDS (LDS dest wave-uniform base; HW adds lane*16)
__device__ __forceinline__ void glds16(const __hip_bfloat16* g, __hip_bfloat16* l){
  __builtin_amdgcn_global_load_lds(
      (const __attribute__((address_space(1))) void*)g,
      (__attribute__((address_space(3))) void*)l, 16, 0, 0);
}

// ---------------- packing ----------------
__global__ __launch_bounds__(256) void pack_w2(const float* __restrict__ W,
                                               __hip_bfloat16* __restrict__ P){
  int tid = blockIdx.x*256 + threadIdx.x;   // 1024 blocks
  int r = tid >> 8, k = tid & 255;
  float w = W[tid];
  __hip_bfloat16 h = __float2bfloat16(w);
  __hip_bfloat16 l = __float2bfloat16(w - __bfloat162float(h));
  size_t base = (size_t)r*512;
  P[base + k] = h; P[base + 256 + k] = l;
}
__global__ __launch_bounds__(256) void pack_w0(const float* __restrict__ W,
                                               __hip_bfloat16* __restrict__ P){
  int tid = blockIdx.x*256 + threadIdx.x;   // 64 blocks
  int r = tid >> 4, k = tid & 15;
  float w = W[tid];
  __hip_bfloat16 h = __float2bfloat16(w);
  __hip_bfloat16 l = __float2bfloat16(w - __bfloat162float(h));
  size_t base = (size_t)r*64;
  P[base + k] = h; P[base + 16 + k] = h; P[base + 32 + k] = l;
  P[base + 48 + k] = __float2bfloat16(0.0f);
}
__global__ __launch_bounds__(256) void pack_x(const float* __restrict__ x,
                                              __hip_bfloat16* __restrict__ Xp){
  int tid = blockIdx.x*256 + threadIdx.x;   // 2048 blocks
  const float* xr = x + (size_t)tid*16;
  __hip_bfloat16* o = Xp + (size_t)tid*64;
  for (int k=0;k<16;k++){
    float v = xr[k];
    __hip_bfloat16 h = __float2bfloat16(v);
    __hip_bfloat16 l = __float2bfloat16(v - __bfloat162float(h));
    o[k] = h; o[16+k] = l; o[32+k] = h; o[48+k] = __float2bfloat16(0.0f);
  }
}
__global__ __launch_bounds__(256) void recon_nf(const __hip_bfloat16* __restrict__ hi,
    const __hip_bfloat16* __restrict__ lo, float* __restrict__ nf){
  int tid = blockIdx.x*256 + threadIdx.x;
  nf[tid] = __bfloat162float(hi[tid]) + __bfloat162float(lo[tid]);
}

// ---------------- GEMM segment: pipelined 2-phase, A direct to regs ----------------
// A-tiles (h rows) are PRIVATE per wave -> loaded global->VGPR directly (no LDS).
// B-tiles (weights, shared by all 4 waves) stay in LDS, double-buffered, staged
// via glds16 with the source-side XOR swizzle. Per 64-K chunk: ONE barrier; the
// next chunk's A-register loads + B-stage are issued before this chunk's MFMAs,
// so the vmcnt(0) at the next __syncthreads lands after a full chunk of compute.
// MFMA operand values and accumulation order are bit-identical to the drain
// version (same logical fragments, same op sequence).
__device__ __forceinline__ void mm_merged(
    const __hip_bfloat16* __restrict__ Ahi, const __hip_bfloat16* __restrict__ Alo,
    size_t lda,
    const __hip_bfloat16* __restrict__ Bhi, const __hip_bfloat16* __restrict__ Blo,
    size_t ldb,
    int m0, int j0, int wv, int lane, int rr, int sw8, int frow,
    f32x4 (&acc)[2][4],
    __hip_bfloat16* BsH0, __hip_bfloat16* BsL0,
    __hip_bfloat16* BsH1, __hip_bfloat16* BsL1)
{
  const size_t brow = (size_t)(wv*256 + j0 + rr)*ldb + sw8;
  const int aoff = ((lane>>4)<<3);                      // k-slice within row
  const size_t ar0 = (size_t)(m0 + wv*32 + frow)*lda + aoff;
  const size_t ar1 = ar0 + (size_t)16*lda;

  short8 pah0[2][2], pah1[2][2], pal0[2][2], pal1[2][2];  // [parity][w2]

  // prologue: chunk 0 A-regs + B-stage into buffer 0
  #pragma unroll
  for (int w2=0; w2<2; ++w2){
    pah0[0][w2] = ld8bf(Ahi + ar0 + w2*32);
    pah1[0][w2] = ld8bf(Ahi + ar1 + w2*32);
    pal0[0][w2] = ld8bf(Alo + ar0 + w2*32);
    pal1[0][w2] = ld8bf(Alo + ar1 + w2*32);
  }
  {
    const __hip_bfloat16* Bb1 = Bhi + brow;
    __hip_bfloat16* Bd1 = BsH0 + (wv<<4)*64;
    glds16(Bb1, Bd1); glds16(Bb1 + (size_t)8*ldb, Bd1 + 8*64);
    const __hip_bfloat16* Bb2 = Blo + brow;
    __hip_bfloat16* Bd2 = BsL0 + (wv<<4)*64;
    glds16(Bb2, Bd2); glds16(Bb2 + (size_t)8*ldb, Bd2 + 8*64);
  }

  #pragma unroll
  for (int c=0; c<4; ++c){
    __syncthreads();                 // drains chunk c's A-regs + B LDS (vmcnt0)
    if (c < 3){                      // prefetch chunk c+1 into other parity
      const int kb = (c+1)*64;
      const int pn = (c+1)&1;
      #pragma unroll
      for (int w2=0; w2<2; ++w2){
        pah0[pn][w2] = ld8bf(Ahi + ar0 + kb + w2*32);
        pah1[pn][w2] = ld8bf(Ahi + ar1 + kb + w2*32);
        pal0[pn][w2] = ld8bf(Alo + ar0 + kb + w2*32);
        pal1[pn][w2] = ld8bf(Alo + ar1 + kb + w2*32);
      }
      __hip_bfloat16* BdH = (pn ? BsH1 : BsH0) + (wv<<4)*64;
      __hip_bfloat16* BdL = (pn ? BsL1 : BsL0) + (wv<<4)*64;
      const __hip_bfloat16* Bb1 = Bhi + brow + kb;
      glds16(Bb1, BdH); glds16(Bb1 + (size_t)8*ldb, BdH + 8*64);
      const __hip_bfloat16* Bb2 = Blo + brow + kb;
      glds16(Bb2, BdL); glds16(Bb2 + (size_t)8*ldb, BdL + 8*64);
    }
    const int p = c&1;
    const __hip_bfloat16* BH = p ? BsH1 : BsH0;
    const __hip_bfloat16* BL = p ? BsL1 : BsL0;
    #pragma unroll
    for (int w2=0; w2<2; ++w2){
      const int sl8 = ((((w2<<2) + (lane>>4)) ^ (lane&7)) << 3);
      #pragma unroll
      for (int g=0; g<4; ++g){
        short8 bh = ld8bf(&BH[((g<<4) + frow)*64 + sl8]);
        acc[0][g] = __builtin_amdgcn_mfma_f32_16x16x32_bf16(pah0[p][w2], bh, acc[0][g], 0,0,0);
        acc[1][g] = __builtin_amdgcn_mfma_f32_16x16x32_bf16(pah1[p][w2], bh, acc[1][g], 0,0,0);
        acc[0][g] = __builtin_amdgcn_mfma_f32_16x16x32_bf16(pal0[p][w2], bh, acc[0][g], 0,0,0);
        acc[1][g] = __builtin_amdgcn_mfma_f32_16x16x32_bf16(pal1[p][w2], bh, acc[1][g], 0,0,0);
        short8 bl = ld8bf(&BL[((g<<4) + frow)*64 + sl8]);
        acc[0][g] = __builtin_amdgcn_mfma_f32_16x16x32_bf16(pah0[p][w2], bl, acc[0][g], 0,0,0);
        acc[1][g] = __builtin_amdgcn_mfma_f32_16x16x32_bf16(pah1[p][w2], bl, acc[1][g], 0,0,0);
      }
    }
  }
}

// single-B, one 64-panel (K=64 x-chunk): A direct to regs, B staged once.
__device__ __forceinline__ void mm_single64(
    const __hip_bfloat16* __restrict__ A, size_t lda,
    const __hip_bfloat16* __restrict__ B, size_t ldb,
    int m0, int j0, int wv, int lane, int rr, int sw8, int frow,
    f32x4 (&acc)[2][4],
    __hip_bfloat16* Bh0)
{
  const int aoff = ((lane>>4)<<3);
  const size_t ar0 = (size_t)(m0 + wv*32 + frow)*lda + aoff;
  const size_t ar1 = ar0 + (size_t)16*lda;
  short8 a0[2], a1[2];
  #pragma unroll
  for (int w2=0; w2<2; ++w2){
    a0[w2] = ld8bf(A + ar0 + w2*32);
    a1[w2] = ld8bf(A + ar1 + w2*32);
  }
  {
    const __hip_bfloat16* Bb1 = B + (size_t)(wv*256 + j0 + rr)*ldb + sw8;
    __hip_bfloat16* Bd1 = Bh0 + (wv<<4)*64;
    glds16(Bb1, Bd1); glds16(Bb1 + (size_t)8*ldb, Bd1 + 8*64);
  }
  __syncthreads();
  #pragma unroll
  for (int w2=0; w2<2; ++w2){
    const int sl8 = ((((w2<<2) + (lane>>4)) ^ (lane&7)) << 3);
    #pragma unroll
    for (int g=0; g<4; ++g){
      short8 b1 = ld8bf(&Bh0[((g<<4) + frow)*64 + sl8]);
      acc[0][g] = __builtin_amdgcn_mfma_f32_16x16x32_bf16(a0[w2], b1, acc[0][g], 0,0,0);
      acc[1][g] = __builtin_amdgcn_mfma_f32_16x16x32_bf16(a1[w2], b1, acc[1][g], 0,0,0);
    }
  }
}

// ---------------- fused two-layer skewed LSTM step ----------------
__global__ __launch_bounds__(256, 2) void lstm2_step(
    int t,
    const __hip_bfloat16* __restrict__ Xp,
    const __hip_bfloat16* __restrict__ P0ih,
    const __hip_bfloat16* __restrict__ P0hh,
    const __hip_bfloat16* __restrict__ P1ih,
    const __hip_bfloat16* __restrict__ P1hh,
    const float* __restrict__ bih0, const float* __restrict__ bhh0,
    const float* __restrict__ bih1, const float* __restrict__ bhh1,
    const __hip_bfloat16* __restrict__ h0p_hi, const __hip_bfloat16* __restrict__ h0p_lo,
    __hip_bfloat16* __restrict__ h0o_hi, __hip_bfloat16* __restrict__ h0o_lo,
    const __hip_bfloat16* __restrict__ h1p_hi, const __hip_bfloat16* __restrict__ h1p_lo,
    __hip_bfloat16* __restrict__ h1o_hi, __hip_bfloat16* __restrict__ h1o_lo,
    float* __restrict__ c0, float* __restrict__ c1)
{
  __shared__ __align__(16) __hip_bfloat16 BsH0[64*64];   // 8 KB
  __shared__ __align__(16) __hip_bfloat16 BsL0[64*64];   // 8 KB
  __shared__ __align__(16) __hip_bfloat16 BsH1[64*64];   // 8 KB
  __shared__ __align__(16) __hip_bfloat16 BsL1[64*64];   // 8 KB

  const int bid = blockIdx.x;
  const int xcd = bid & 7;            // presumed XCD (round-robin dispatch)
  const int slot = bid >> 3;          // 0..63 within this XCD
  const bool isL0 = xcd < 4;
  if (isL0 && t >= TT) return;
  if (!isL0 && t == 0) return;
  const int lg = isL0 ? xcd : (xcd - 4);
  const int jg = ((lg & 1) << 3) + (slot & 7);
  const int mg = ((lg >> 1) << 3) + (slot >> 3);
  const int m0 = mg << 7;
  const int j0 = jg << 4;
  const int lane = threadIdx.x & 63, wv = threadIdx.x >> 6;
  const int rr = lane >> 3;
  const int sw8 = (((lane & 7) ^ rr) << 3);     // source-side XOR swizzle
  const int frow = lane & 15;

  f32x4 acc[2][4] = {};                 // [m-subtile][gate]

  if (isL0){
    if (t != 0){
      mm_merged(h0p_hi, h0p_lo, 256, P0hh, P0hh+256, 512,
                m0, j0, wv, lane, rr, sw8, frow, acc, BsH0, BsL0, BsH1, BsL1);
    }
    mm_single64(Xp + (size_t)t*64, (size_t)TT*64, P0ih, 64,
                m0, j0, wv, lane, rr, sw8, frow, acc, BsH0);
  } else {
    mm_merged(h0p_hi, h0p_lo, 256, P1ih, P1ih+256, 512,
              m0, j0, wv, lane, rr, sw8, frow, acc, BsH0, BsL0, BsH1, BsL1);
    if (t != 1){
      mm_merged(h1p_hi, h1p_lo, 256, P1hh, P1hh+256, 512,
                m0, j0, wv, lane, rr, sw8, frow, acc, BsH0, BsL0, BsH1, BsL1);
    }
  }

  // epilogue: lane holds all 4 gates. C map: col=lane&15, row=(lane>>4)*4+r
  const int j = j0 + frow;
  const float* bih = isL0 ? bih0 : bih1;
  const float* bhh = isL0 ? bhh0 : bhh1;
  float* cst = isL0 ? c0 : c1;
  __hip_bfloat16* ohi = isL0 ? h0o_hi : h1o_hi;
  __hip_bfloat16* olo = isL0 ? h0o_lo : h1o_lo;
  const int first = isL0 ? (t==0) : (t==1);
  const float b0 = bih[j]        + bhh[j];
  const float b1 = bih[HH + j]   + bhh[HH + j];
  const float b2 = bih[2*HH + j] + bhh[2*HH + j];
  const float b3 = bih[3*HH + j] + bhh[3*HH + j];
  #pragma unroll
  for (int mt=0; mt<2; ++mt){
    const int mrb = m0 + wv*32 + mt*16 + ((lane>>4)<<2);
    #pragma unroll
    for (int r=0; r<4; ++r){
      const size_t mi = (size_t)(mrb + r)*HH + j;
      float gi = acc[mt][0][r] + b0;
      float gf = acc[mt][1][r] + b1;
      float gg = acc[mt][2][r] + b2;
      float go = acc[mt][3][r] + b3;
      float cold = first ? 0.f : cst[mi];
      float cn = sigmoidf_(gf)*cold + sigmoidf_(gi)*tanhf(gg);
      float hv = sigmoidf_(go)*tanhf(cn);
      cst[mi] = cn;
      __hip_bfloat16 hb = __float2bfloat16(hv);
      ohi[mi] = hb;
      olo[mi] = __float2bfloat16(hv - __bfloat162float(hb));
    }
  }
}

// ---------------- fp32 tail (unchanged, proven) ----------------
__global__ __launch_bounds__(256) void gemm_nn(
    float* __restrict__ C, const float* __restrict__ A, const float* __restrict__ B,
    int K, int lda, int ldb, int ldc, int relu)
{
  __shared__ float As_[16][68];
  __shared__ float Bs_[16][64];
  float acc[4][4] = {};
  const int tx = threadIdx.x;
  const int m0 = blockIdx.y<<6, n0 = blockIdx.x<<6;
  const int am = tx>>2, ak = (tx&3)<<2;
  const int bk = tx>>4, bn = (tx&15)<<2;
  const int mm = (tx>>4)<<2, nc = (tx&15)<<2;
  for (int kb=0; kb<K; kb+=16){
    float4 av = *reinterpret_cast<const float4*>(A + (size_t)(m0+am)*lda + kb + ak);
    As_[ak][am]=av.x; As_[ak+1][am]=av.y; As_[ak+2][am]=av.z; As_[ak+3][am]=av.w;
    *reinterpret_cast<float4*>(&Bs_[bk][bn]) =
      *reinterpret_cast<const float4*>(B + (size_t)(kb+bk)*ldb + n0 + bn);
    __syncthreads();
    #pragma unroll
    for (int k=0;k<16;k++){
      float4 a4 = *reinterpret_cast<const float4*>(&As_[k][mm]);
      float4 b4 = *reinterpret_cast<const float4*>(&Bs_[k][nc]);
      acc[0][0]=fmaf(a4.x,b4.x,acc[0][0]); acc[0][1]=fmaf(a4.x,b4.y,acc[0][1]);
      acc[0][2]=fmaf(a4.x,b4.z,acc[0][2]); acc[0][3]=fmaf(a4.x,b4.w,acc[0][3]);
      acc[1][0]=fmaf(a4.y,b4.x,acc[1][0]); acc[1][1]=fmaf(a4.y,b4.y,acc[1][1]);
      acc[1][2]=fmaf(a4.y,b4.z,acc[1][2]); acc[1][3]=fmaf(a4.y,b4.w,acc[1][3]);
      acc[2][0]=fmaf(a4.z,b4.x,acc[2][0]); acc[2][1]=fmaf(a4.z,b4.y,acc[2][1]);
      acc[2][2]=fmaf(a4.z,b4.z,acc[2][2]); acc[2][3]=fmaf(a4.z,b4.w,acc[2][3]);
      acc[3][0]=fmaf(a4.w,b4.x,acc[3][0]); acc[3][1]=fmaf(a4.w,b4.y,acc[3][1]);
      acc[3][2]=fmaf(a4.w,b4.z,acc[3][2]); acc[3][3]=fmaf(a4.w,b4.w,acc[3][3]);
    }
    __syncthreads();
  }
  #pragma unroll
  for (int r=0;r<4;r++){
    float4 v = make_float4(acc[r][0],acc[r][1],acc[r][2],acc[r][3]);
    if (relu){ v.x=fmaxf(v.x,0.f); v.y=fmaxf(v.y,0.f); v.z=fmaxf(v.z,0.f); v.w=fmaxf(v.w,0.f); }
    *reinterpret_cast<float4*>(C + (size_t)(m0+mm+r)*ldc + n0 + nc) = v;
  }
}

__global__ __launch_bounds__(256) void gemm_nt(
    float* __restrict__ C, const float* __restrict__ A, const float* __restrict__ B,
    int K, int lda, int ldb, int ldc)
{
  __shared__ float As_[16][68];
  __shared__ float Bs_[16][68];
  float acc[4][4] = {};
  const int tx = threadIdx.x;
  const int m0 = blockIdx.y<<6, n0 = blockIdx.x<<6;
  const int am = tx>>2, ak = (tx&3)<<2;
  const int mm = (tx>>4)<<2, nc = (tx&15)<<2;
  for (int kb=0; kb<K; kb+=16){
    float4 av = *reinterpret_cast<const float4*>(A + (size_t)(m0+am)*lda + kb + ak);
    As_[ak][am]=av.x; As_[ak+1][am]=av.y; As_[ak+2][am]=av.z; As_[ak+3][am]=av.w;
    float4 bv = *reinterpret_cast<const float4*>(B + (size_t)(n0+am)*ldb + kb + ak);
    Bs_[ak][am]=bv.x; Bs_[ak+1][am]=bv.y; Bs_[ak+2][am]=bv.z; Bs_[ak+3][am]=bv.w;
    __syncthreads();
    #pragma unroll
    for (int k=0;k<16;k++){
      float4 a4 = *reinterpret_cast<const float4*>(&As_[k][mm]);
      float4 b4 = *reinterpret_cast<const float4*>(&Bs_[k][nc]);
      acc[0][0]=fmaf(a4.x,b4.x,acc[0][0]); acc[0][1]=fmaf(a4.x,b4.y,acc[0][1]);
      acc[0][2]=fmaf(a4.x,b4.z,acc[0][2]); acc[0][3]=fmaf(a4.x,b4.w,acc[0][3]);
      acc[1][0]=fmaf(a4.y,b4.x,acc[1][0]); acc[1][1]=fmaf(a4.y,b4.y,acc[1][1]);
      acc[1][2]=fmaf(a4.y,b4.z,acc[1][2]); acc[1][3]=fmaf(a4.y,b4.w,acc[1][3]);
      acc[2][0]=fmaf(a4.z,b4.x,acc[2][0]); acc[2][1]=fmaf(a4.z,b4.y,acc[2][1]);
      acc[2][2]=fmaf(a4.z,b4.z,acc[2][2]); acc[2][3]=fmaf(a4.z,b4.w,acc[2][3]);
      acc[3][0]=fmaf(a4.w,b4.x,acc[3][0]); acc[3][1]=fmaf(a4.w,b4.y,acc[3][1]);
      acc[3][2]=fmaf(a4.w,b4.z,acc[3][2]); acc[3][3]=fmaf(a4.w,b4.w,acc[3][3]);
    }
    __syncthreads();
  }
  #pragma unroll
  for (int r=0;r<4;r++){
    float4 v = make_float4(acc[r][0],acc[r][1],acc[r][2],acc[r][3]);
    *reinterpret_cast<float4*>(C + (size_t)(m0+mm+r)*ldc + n0 + nc) = v;
  }
}

__global__ __launch_bounds__(256) void rowstat(const float* __restrict__ nf,
    float* __restrict__ xc, float* __restrict__ dvec)
{
  __shared__ float red[256];
  int n = blockIdx.x, tx = threadIdx.x;
  float v = nf[(size_t)n*HH + tx];
  red[tx] = v; __syncthreads();
  for (int s=128; s>0; s>>=1){ if (tx<s) red[tx]+=red[tx+s]; __syncthreads(); }
  float mean = red[0] * (1.0f/HH);
  __syncthreads();
  float d = v - mean;
  xc[(size_t)n*HH + tx] = d;
  red[tx] = d*d; __syncthreads();
  for (int s=128; s>0; s>>=1){ if (tx<s) red[tx]+=red[tx+s]; __syncthreads(); }
  if (tx==0) dvec[n] = sqrtf(red[0]);
}

__global__ __launch_bounds__(256) void rowsum(const float* __restrict__ cov,
    const float* __restrict__ dvec, float* __restrict__ dinv)
{
  __shared__ float red[256];
  int i = blockIdx.x, tx = threadIdx.x;
  float di = dvec[i];
  float s = 0.f;
  for (int jj=tx; jj<NN; jj+=256){
    float r = cov[(size_t)i*NN + jj] / (di * dvec[jj]);
    if (r != r) r = 0.f; else r = fminf(1.f, fmaxf(-1.f, r));
    s += r;
  }
  red[tx]=s; __syncthreads();
  for (int st=128; st>0; st>>=1){ if (tx<st) red[tx]+=red[tx+st]; __syncthreads(); }
  if (tx==0){
    float tot = red[0] + 1.0f;
    float p = powf(tot, -0.5f);
    if (isinf(p)) p = 0.f;
    dinv[i] = p;
  }
}

__global__ __launch_bounds__(256) void adjnorm(float* __restrict__ cov,
    const float* __restrict__ dvec, const float* __restrict__ dinv)
{
  size_t idx = (size_t)blockIdx.x*256 + threadIdx.x;
  int i = (int)(idx >> 11), jj = (int)(idx & (NN-1));
  float r = cov[idx] / (dvec[i]*dvec[jj]);
  if (r != r) r = 0.f; else r = fminf(1.f, fmaxf(-1.f, r));
  if (i==jj) r += 1.f;
  cov[idx] = dinv[i]*r*dinv[jj];
}

__global__ __launch_bounds__(128) void predk(const float* __restrict__ G2,
    const float* __restrict__ Wfc, const float* __restrict__ bfc, float* __restrict__ out)
{
  int n = blockIdx.x, tx = threadIdx.x;
  float v = G2[(size_t)n*128 + tx] * Wfc[tx];
  for (int off=32; off>0; off>>=1) v += __shfl_down(v, off);
  __shared__ float p[2];
  if ((tx&63)==0) p[tx>>6] = v;
  __syncthreads();
  if (tx==0) out[n] = p[0] + p[1] + bfc[0];
}

extern "C" void kernel_launch(void* const* d_in, const int* in_sizes, int n_in,
                              void* d_out, int out_size, void* d_ws, size_t ws_size,
                              hipStream_t stream)
{
  const float* x    = (const float*)d_in[0];
  const float* Wih0 = (const float*)d_in[1];
  const float* Whh0 = (const float*)d_in[2];
  const float* bih0 = (const float*)d_in[3];
  const float* bhh0 = (const float*)d_in[4];
  const float* Wih1 = (const float*)d_in[5];
  const float* Whh1 = (const float*)d_in[6];
  const float* bih1 = (const float*)d_in[7];
  const float* bhh1 = (const float*)d_in[8];
  const float* Wg1  = (const float*)d_in[9];
  const float* Wg2  = (const float*)d_in[10];
  const float* Wfc  = (const float*)d_in[11];
  const float* bfc  = (const float*)d_in[12];
  float* out = (float*)d_out;

  char* w = (char*)d_ws;
  auto alloc = [&](size_t bytes){ char* p = w; w += (bytes + 255) & ~(size_t)255; return p; };
  __hip_bfloat16* Xp   = (__hip_bfloat16*)alloc((size_t)NN*TT*64*2);
  __hip_bfloat16* P0hh = (__hip_bfloat16*)alloc((size_t)1024*512*2);
  __hip_bfloat16* P1ih = (__hip_bfloat16*)alloc((size_t)1024*512*2);
  __hip_bfloat16* P1hh = (__hip_bfloat16*)alloc((size_t)1024*512*2);
  __hip_bfloat16* P0ih = (__hip_bfloat16*)alloc((size_t)1024*64*2);
  __hip_bfloat16 *H0hi[2], *H0lo[2], *H1hi[2], *H1lo[2];
  for (int i=0;i<2;i++){ H0hi[i]=(__hip_bfloat16*)alloc((size_t)NN*HH*2);
                         H0lo[i]=(__hip_bfloat16*)alloc((size_t)NN*HH*2); }
  for (int i=0;i<2;i++){ H1hi[i]=(__hip_bfloat16*)alloc((size_t)NN*HH*2);
                         H1lo[i]=(__hip_bfloat16*)alloc((size_t)NN*HH*2); }
  float* c0   = (float*)alloc((size_t)NN*HH*4);
  float* c1   = (float*)alloc((size_t)NN*HH*4);
  float* nf   = (float*)alloc((size_t)NN*HH*4);
  float* xc   = (float*)alloc((size_t)NN*HH*4);
  float* cov  = (float*)alloc((size_t)NN*NN*4);
  float* t1   = (float*)alloc((size_t)NN*HH*4);
  float* G1   = (float*)alloc((size_t)NN*HH*4);
  float* t2   = (float*)alloc((size_t)NN*128*4);
  float* G2   = (float*)alloc((size_t)NN*128*4);
  float* dvec = (float*)alloc((size_t)NN*4);
  float* dinv = (float*)alloc((size_t)NN*4);

  hipLaunchKernelGGL(pack_w2, dim3(1024), dim3(256), 0, stream, Whh0, P0hh);
  hipLaunchKernelGGL(pack_w2, dim3(1024), dim3(256), 0, stream, Wih1, P1ih);
  hipLaunchKernelGGL(pack_w2, dim3(1024), dim3(256), 0, stream, Whh1, P1hh);
  hipLaunchKernelGGL(pack_w0, dim3(64),   dim3(256), 0, stream, Wih0, P0ih);
  hipLaunchKernelGGL(pack_x,  dim3(2048), dim3(256), 0, stream, x, Xp);

  // skewed recurrence: launch t runs L0(t) and L1(t-1)
  for (int t=0; t<=TT; ++t){
    const __hip_bfloat16 *h0p_hi = H0hi[(t+1)&1], *h0p_lo = H0lo[(t+1)&1];
    __hip_bfloat16 *h0o_hi = H0hi[t&1], *h0o_lo = H0lo[t&1];
    const __hip_bfloat16 *h1p_hi = H1hi[t&1], *h1p_lo = H1lo[t&1];
    __hip_bfloat16 *h1o_hi = H1hi[(t+1)&1], *h1o_lo = H1lo[(t+1)&1];
    hipLaunchKernelGGL(lstm2_step, dim3(512), dim3(256), 0, stream,
        t, Xp, P0ih, P0hh, P1ih, P1hh, bih0, bhh0, bih1, bhh1,
        h0p_hi, h0p_lo, h0o_hi, h0o_lo, h1p_hi, h1p_lo, h1o_hi, h1o_lo, c0, c1);
  }
  // final h1 (step 255, written at launch t=256) lives in H1[1]
  hipLaunchKernelGGL(recon_nf, dim3(2048), dim3(256), 0, stream, H1hi[1], H1lo[1], nf);

  hipLaunchKernelGGL(rowstat, dim3(NN), dim3(256), 0, stream, nf, xc, dvec);
  hipLaunchKernelGGL(gemm_nt, dim3(NN/64, NN/64), dim3(256), 0, stream,
      cov, xc, xc, HH, HH, HH, NN);
  hipLaunchKernelGGL(rowsum, dim3(NN), dim3(256), 0, stream, cov, dvec, dinv);
  hipLaunchKernelGGL(adjnorm, dim3(NN*NN/256), dim3(256), 0, stream, cov, dvec, dinv);

  hipLaunchKernelGGL(gemm_nn, dim3(HH/64, NN/64), dim3(256), 0, stream,
      t1, nf, Wg1, HH, HH, HH, HH, 0);
  hipLaunchKernelGGL(gemm_nn, dim3(HH/64, NN/64), dim3(256), 0, stream,
      G1, cov, t1, NN, NN, HH, HH, 1);
  hipLaunchKernelGGL(gemm_nn, dim3(128/64, NN/64), dim3(256), 0, stream,
      t2, G1, Wg2, HH, HH, 128, 128, 0);
  hipLaunchKernelGGL(gemm_nn, dim3(128/64, NN/64), dim3(256), 0, stream,
      G2, cov, t2, NN, NN, 128, 128, 0);
  hipLaunchKernelGGL(predk, dim3(NN), dim3(128), 0, stream, G2, Wfc, bfc, out);
}

// Round 3
// 6362.162 us; speedup vs baseline: 4.0286x; 1.0061x over previous
//
#include <hip/hip_runtime.h>
#include <hip/hip_bf16.h>
#include <cmath>

#define NN 2048
#define TT 256
#define DD 16
#define HH 256

typedef __attribute__((ext_vector_type(8))) short short8;
typedef __attribute__((ext_vector_type(4))) float f32x4;

__device__ __forceinline__ float sigmoidf_(float x){ return 1.0f/(1.0f+expf(-x)); }

// async 16B/lane global->LDS (LDS dest wave-uniform base; HW adds lane*16)
__device__ __forceinline__ void glds16(const __hip_bfloat16* g, __hip_bfloat16* l){
  __builtin_amdgcn_global_load_lds(
      (const __attribute__((address_space(1))) void*)g,
      (__attribute__((address_space(3))) void*)l, 16, 0, 0);
}
// L2 warm touch: per-lane arbitrary source offset, junk LDS dest (never read).
// One call touches up to 64 distinct 128B lines, fully async (no reg result,
// no wait until the next __syncthreads vmcnt drain).
__device__ __forceinline__ void warmg(const void* g, size_t laneoff, __hip_bfloat16* ws){
  glds16((const __hip_bfloat16*)((const char*)g + laneoff), ws);
}

// ---------------- packing ----------------
// W (1024x256) -> P (1024x512): [hi | lo]
__global__ __launch_bounds__(256) void pack_w2(const float* __restrict__ W,
                                               __hip_bfloat16* __restrict__ P){
  int tid = blockIdx.x*256 + threadIdx.x;   // 1024 blocks
  int r = tid >> 8, k = tid & 255;
  float w = W[tid];
  __hip_bfloat16 h = __float2bfloat16(w);
  __hip_bfloat16 l = __float2bfloat16(w - __bfloat162float(h));
  size_t base = (size_t)r*512;
  P[base + k] = h; P[base + 256 + k] = l;
}
// Wih0 (1024 x 16) -> (1024 x 64): [hi | hi | lo | 0] (pairs with x [hi|lo|hi|0])
__global__ __launch_bounds__(256) void pack_w0(const float* __restrict__ W,
                                               __hip_bfloat16* __restrict__ P){
  int tid = blockIdx.x*256 + threadIdx.x;   // 64 blocks
  int r = tid >> 4, k = tid & 15;
  float w = W[tid];
  __hip_bfloat16 h = __float2bfloat16(w);
  __hip_bfloat16 l = __float2bfloat16(w - __bfloat162float(h));
  size_t base = (size_t)r*64;
  P[base + k] = h; P[base + 16 + k] = h; P[base + 32 + k] = l;
  P[base + 48 + k] = __float2bfloat16(0.0f);
}
// x (N,T,16) -> Xp (N,T,64): [hi | lo | hi | 0]
__global__ __launch_bounds__(256) void pack_x(const float* __restrict__ x,
                                              __hip_bfloat16* __restrict__ Xp){
  int tid = blockIdx.x*256 + threadIdx.x;   // 2048 blocks
  const float* xr = x + (size_t)tid*16;
  __hip_bfloat16* o = Xp + (size_t)tid*64;
  for (int k=0;k<16;k++){
    float v = xr[k];
    __hip_bfloat16 h = __float2bfloat16(v);
    __hip_bfloat16 l = __float2bfloat16(v - __bfloat162float(h));
    o[k] = h; o[16+k] = l; o[32+k] = h; o[48+k] = __float2bfloat16(0.0f);
  }
}
__global__ __launch_bounds__(256) void recon_nf(const __hip_bfloat16* __restrict__ hi,
    const __hip_bfloat16* __restrict__ lo, float* __restrict__ nf){
  int tid = blockIdx.x*256 + threadIdx.x;
  nf[tid] = __bfloat162float(hi[tid]) + __bfloat162float(lo[tid]);
}

// ---------------- GEMM segment: merged-A chunks, drain pattern ----------------
// Block tile: 128 m x 16 j x 4 gates. 4 waves; wave stages its 32 m-rows of
// A-hi AND A-lo plus gate-group wv's 16 rows of B-hi and B-lo per k64 chunk.
// Per chunk: stage(12 glds16) -> sync (drains) -> 3-pass MFMA (hi*Bhi, lo*Bhi,
// hi*Blo) -> sync. No load outstanding across a barrier->MFMA boundary.
__device__ __forceinline__ void mm_merged(
    const __hip_bfloat16* __restrict__ Ahi, const __hip_bfloat16* __restrict__ Alo,
    size_t lda,
    const __hip_bfloat16* __restrict__ Bhi, const __hip_bfloat16* __restrict__ Blo,
    size_t ldb, int Klen,
    int m0, int j0, int wv, int lane, int rr, int sw8, int frow,
    f32x4 (&acc)[2][4],
    __hip_bfloat16* AsH, __hip_bfloat16* AsL,
    __hip_bfloat16* BsH, __hip_bfloat16* BsL)
{
  const size_t arow = (size_t)(m0 + wv*32 + rr)*lda + sw8;
  const size_t brow = (size_t)(wv*256 + j0 + rr)*ldb + sw8;
  for (int kb=0; kb<Klen; kb+=64){
    {
      const __hip_bfloat16* AbH = Ahi + arow + kb;
      __hip_bfloat16* AdH = AsH + (wv*32)*64;
      #pragma unroll
      for (int c2=0;c2<4;c2++) glds16(AbH + (size_t)(c2*8)*lda, AdH + c2*8*64);
      const __hip_bfloat16* AbL = Alo + arow + kb;
      __hip_bfloat16* AdL = AsL + (wv*32)*64;
      #pragma unroll
      for (int c2=0;c2<4;c2++) glds16(AbL + (size_t)(c2*8)*lda, AdL + c2*8*64);
      const __hip_bfloat16* Bb1 = Bhi + brow + kb;
      __hip_bfloat16* Bd1 = BsH + (wv<<4)*64;
      glds16(Bb1, Bd1); glds16(Bb1 + (size_t)8*ldb, Bd1 + 8*64);
      const __hip_bfloat16* Bb2 = Blo + brow + kb;
      __hip_bfloat16* Bd2 = BsL + (wv<<4)*64;
      glds16(Bb2, Bd2); glds16(Bb2 + (size_t)8*ldb, Bd2 + 8*64);
    }
    __syncthreads();          // drains this chunk's loads
    #pragma unroll
    for (int w2=0; w2<2; ++w2){
      const int sl8 = ((((w2<<2) + (lane>>4)) ^ (lane&7)) << 3);
      short8 ah0 = *(const short8*)&AsH[(wv*32 +      frow)*64 + sl8];
      short8 ah1 = *(const short8*)&AsH[(wv*32 + 16 + frow)*64 + sl8];
      short8 al0 = *(const short8*)&AsL[(wv*32 +      frow)*64 + sl8];
      short8 al1 = *(const short8*)&AsL[(wv*32 + 16 + frow)*64 + sl8];
      #pragma unroll
      for (int g=0; g<4; ++g){
        short8 bh = *(const short8*)&BsH[((g<<4) + frow)*64 + sl8];
        acc[0][g] = __builtin_amdgcn_mfma_f32_16x16x32_bf16(ah0, bh, acc[0][g], 0,0,0);
        acc[1][g] = __builtin_amdgcn_mfma_f32_16x16x32_bf16(ah1, bh, acc[1][g], 0,0,0);
        acc[0][g] = __builtin_amdgcn_mfma_f32_16x16x32_bf16(al0, bh, acc[0][g], 0,0,0);
        acc[1][g] = __builtin_amdgcn_mfma_f32_16x16x32_bf16(al1, bh, acc[1][g], 0,0,0);
        short8 bl = *(const short8*)&BsL[((g<<4) + frow)*64 + sl8];
        acc[0][g] = __builtin_amdgcn_mfma_f32_16x16x32_bf16(ah0, bl, acc[0][g], 0,0,0);
        acc[1][g] = __builtin_amdgcn_mfma_f32_16x16x32_bf16(ah1, bl, acc[1][g], 0,0,0);
      }
    }
    __syncthreads();
  }
}

// single-B, one 64-panel (for the K=64 x-chunk) — exact R8 shape
__device__ __forceinline__ void mm_single64(
    const __hip_bfloat16* __restrict__ A, size_t lda,
    const __hip_bfloat16* __restrict__ B, size_t ldb,
    int m0, int j0, int wv, int lane, int rr, int sw8, int frow,
    f32x4 (&acc)[2][4],
    __hip_bfloat16* As0, __hip_bfloat16* Bh0)
{
  {
    const __hip_bfloat16* Ab = A + (size_t)(m0 + wv*32 + rr)*lda + sw8;
    __hip_bfloat16* Ad = As0 + (wv*32)*64;
    #pragma unroll
    for (int c2=0;c2<4;c2++) glds16(Ab + (size_t)(c2*8)*lda, Ad + c2*8*64);
    const __hip_bfloat16* Bb1 = B + (size_t)(wv*256 + j0 + rr)*ldb + sw8;
    __hip_bfloat16* Bd1 = Bh0 + (wv<<4)*64;
    glds16(Bb1, Bd1); glds16(Bb1 + (size_t)8*ldb, Bd1 + 8*64);
  }
  __syncthreads();
  #pragma unroll
  for (int w2=0; w2<2; ++w2){
    const int sl8 = ((((w2<<2) + (lane>>4)) ^ (lane&7)) << 3);
    short8 a0 = *(const short8*)&As0[(wv*32 +      frow)*64 + sl8];
    short8 a1 = *(const short8*)&As0[(wv*32 + 16 + frow)*64 + sl8];
    #pragma unroll
    for (int g=0; g<4; ++g){
      short8 b1 = *(const short8*)&Bh0[((g<<4) + frow)*64 + sl8];
      acc[0][g] = __builtin_amdgcn_mfma_f32_16x16x32_bf16(a0, b1, acc[0][g], 0,0,0);
      acc[1][g] = __builtin_amdgcn_mfma_f32_16x16x32_bf16(a1, b1, acc[1][g], 0,0,0);
    }
  }
  __syncthreads();
}

// ---------------- fused two-layer skewed LSTM step (MFMA bf16x3) ----------------
// XCD-aware mapping (round-robin bid->XCD assumed, perf-only): XCDs 0-3 run
// layer0, XCDs 4-7 run layer1. Prologue issues one async 16B touch per 128B
// line of the block's whole step working set (each launch starts L2-cold from
// the dispatch acquire); all L3 misses then resolve concurrently under the
// first chunk's drain instead of serializing chunk-by-chunk.
__global__ __launch_bounds__(256, 2) void lstm2_step(
    int t,
    const __hip_bfloat16* __restrict__ Xp,
    const __hip_bfloat16* __restrict__ P0ih,
    const __hip_bfloat16* __restrict__ P0hh,
    const __hip_bfloat16* __restrict__ P1ih,
    const __hip_bfloat16* __restrict__ P1hh,
    const float* __restrict__ bih0, const float* __restrict__ bhh0,
    const float* __restrict__ bih1, const float* __restrict__ bhh1,
    const __hip_bfloat16* __restrict__ h0p_hi, const __hip_bfloat16* __restrict__ h0p_lo,
    __hip_bfloat16* __restrict__ h0o_hi, __hip_bfloat16* __restrict__ h0o_lo,
    const __hip_bfloat16* __restrict__ h1p_hi, const __hip_bfloat16* __restrict__ h1p_lo,
    __hip_bfloat16* __restrict__ h1o_hi, __hip_bfloat16* __restrict__ h1o_lo,
    float* __restrict__ c0, float* __restrict__ c1)
{
  __shared__ __align__(16) __hip_bfloat16 AsH[128*64];   // 16 KB
  __shared__ __align__(16) __hip_bfloat16 AsL[128*64];   // 16 KB
  __shared__ __align__(16) __hip_bfloat16 BsH[64*64];    // 8 KB
  __shared__ __align__(16) __hip_bfloat16 BsL[64*64];    // 8 KB
  __shared__ __align__(16) __hip_bfloat16 warmS[4*512];  // 4 KB junk dest

  const int bid = blockIdx.x;
  const int xcd = bid & 7;            // presumed XCD (round-robin dispatch)
  const int slot = bid >> 3;          // 0..63 within this XCD
  const bool isL0 = xcd < 4;
  if (isL0 && t >= TT) return;
  if (!isL0 && t == 0) return;
  const int lg = isL0 ? xcd : (xcd - 4);          // 2-bit quadrant id
  const int jg = ((lg & 1) << 3) + (slot & 7);    // 0..15
  const int mg = ((lg >> 1) << 3) + (slot >> 3);  // 0..15
  const int m0 = mg << 7;
  const int j0 = jg << 4;
  const int lane = threadIdx.x & 63, wv = threadIdx.x >> 6;
  const int rr = lane >> 3;
  const int sw8 = (((lane & 7) ^ rr) << 3);     // source-side XOR swizzle
  const int frow = lane & 15;

  // ---- L2 warm prologue (async, junk dest, zero extra unique traffic) ----
  __hip_bfloat16* ws = &warmS[wv*512];
  const size_t lhi = (size_t)lane*128;            // contiguous-region stride
  if (isL0){
    if (t != 0){
      const char* a1 = (const char*)h0p_hi + (size_t)m0*512;   // 128 rows x 512B
      const char* a2 = (const char*)h0p_lo + (size_t)m0*512;
      #pragma unroll
      for (int c2=0;c2<2;c2++){
        warmg(a1, (size_t)(wv*2+c2)*8192 + lhi, ws);
        warmg(a2, (size_t)(wv*2+c2)*8192 + lhi, ws);
      }
      const char* bb = (const char*)P0hh + ((size_t)(wv*256) + j0)*1024; // 16 rows x 1KB
      warmg(bb, lhi, ws);
      warmg(bb, 8192 + lhi, ws);
      if (wv == 0){                                // c0: 128 rows, 1 line each
        const char* cc = (const char*)c0 + ((size_t)m0*256 + (size_t)((j0>>5)<<5))*4;
        warmg(cc, (size_t)lane*1024, ws);
        warmg(cc + (size_t)64*1024, (size_t)lane*1024, ws);
      }
    }
    if (wv == 1){                                  // Xp: 128 rows, 1 line each
      const char* xp = (const char*)Xp + ((size_t)m0*TT + (size_t)t)*128;
      warmg(xp, (size_t)lane*((size_t)TT*128), ws);
      warmg(xp + (size_t)64*TT*128, (size_t)lane*((size_t)TT*128), ws);
    }
    {                                              // P0ih: 16 rows x 128B per wave
      const char* p0 = (const char*)P0ih + ((size_t)(wv*256) + j0)*128;
      warmg(p0, (size_t)(lane&15)*128, ws);
    }
  } else {
    const char* a1 = (const char*)h0p_hi + (size_t)m0*512;
    const char* a2 = (const char*)h0p_lo + (size_t)m0*512;
    #pragma unroll
    for (int c2=0;c2<2;c2++){
      warmg(a1, (size_t)(wv*2+c2)*8192 + lhi, ws);
      warmg(a2, (size_t)(wv*2+c2)*8192 + lhi, ws);
    }
    const char* bb = (const char*)P1ih + ((size_t)(wv*256) + j0)*1024;
    warmg(bb, lhi, ws);
    warmg(bb, 8192 + lhi, ws);
    if (t != 1){
      const char* a3 = (const char*)h1p_hi + (size_t)m0*512;
      const char* a4 = (const char*)h1p_lo + (size_t)m0*512;
      #pragma unroll
      for (int c2=0;c2<2;c2++){
        warmg(a3, (size_t)(wv*2+c2)*8192 + lhi, ws);
        warmg(a4, (size_t)(wv*2+c2)*8192 + lhi, ws);
      }
      const char* bh = (const char*)P1hh + ((size_t)(wv*256) + j0)*1024;
      warmg(bh, lhi, ws);
      warmg(bh, 8192 + lhi, ws);
      if (wv == 0){
        const char* cc = (const char*)c1 + ((size_t)m0*256 + (size_t)((j0>>5)<<5))*4;
        warmg(cc, (size_t)lane*1024, ws);
        warmg(cc + (size_t)64*1024, (size_t)lane*1024, ws);
      }
    }
  }

  f32x4 acc[2][4] = {};                 // [m-subtile][gate]

  if (isL0){
    if (t != 0){
      mm_merged(h0p_hi, h0p_lo, 256, P0hh, P0hh+256, 512, 256,
                m0, j0, wv, lane, rr, sw8, frow, acc, AsH, AsL, BsH, BsL);
    }
    mm_single64(Xp + (size_t)t*64, (size_t)TT*64, P0ih, 64,
                m0, j0, wv, lane, rr, sw8, frow, acc, AsH, BsH);
  } else {
    mm_merged(h0p_hi, h0p_lo, 256, P1ih, P1ih+256, 512, 256,
              m0, j0, wv, lane, rr, sw8, frow, acc, AsH, AsL, BsH, BsL);
    if (t != 1){
      mm_merged(h1p_hi, h1p_lo, 256, P1hh, P1hh+256, 512, 256,
                m0, j0, wv, lane, rr, sw8, frow, acc, AsH, AsL, BsH, BsL);
    }
  }

  // epilogue: lane holds all 4 gates. C map: col=lane&15, row=(lane>>4)*4+r
  const int j = j0 + frow;
  const float* bih = isL0 ? bih0 : bih1;
  const float* bhh = isL0 ? bhh0 : bhh1;
  float* cst = isL0 ? c0 : c1;
  __hip_bfloat16* ohi = isL0 ? h0o_hi : h1o_hi;
  __hip_bfloat16* olo = isL0 ? h0o_lo : h1o_lo;
  const int first = isL0 ? (t==0) : (t==1);
  const float b0 = bih[j]        + bhh[j];
  const float b1 = bih[HH + j]   + bhh[HH + j];
  const float b2 = bih[2*HH + j] + bhh[2*HH + j];
  const float b3 = bih[3*HH + j] + bhh[3*HH + j];
  #pragma unroll
  for (int mt=0; mt<2; ++mt){
    const int mrb = m0 + wv*32 + mt*16 + ((lane>>4)<<2);
    #pragma unroll
    for (int r=0; r<4; ++r){
      const size_t mi = (size_t)(mrb + r)*HH + j;
      float gi = acc[mt][0][r] + b0;
      float gf = acc[mt][1][r] + b1;
      float gg = acc[mt][2][r] + b2;
      float go = acc[mt][3][r] + b3;
      float cold = first ? 0.f : cst[mi];
      float cn = sigmoidf_(gf)*cold + sigmoidf_(gi)*tanhf(gg);
      float hv = sigmoidf_(go)*tanhf(cn);
      cst[mi] = cn;
      __hip_bfloat16 hb = __float2bfloat16(hv);
      ohi[mi] = hb;
      olo[mi] = __float2bfloat16(hv - __bfloat162float(hb));
    }
  }
}

// ---------------- fp32 tail (unchanged, proven) ----------------
__global__ __launch_bounds__(256) void gemm_nn(
    float* __restrict__ C, const float* __restrict__ A, const float* __restrict__ B,
    int K, int lda, int ldb, int ldc, int relu)
{
  __shared__ float As_[16][68];
  __shared__ float Bs_[16][64];
  float acc[4][4] = {};
  const int tx = threadIdx.x;
  const int m0 = blockIdx.y<<6, n0 = blockIdx.x<<6;
  const int am = tx>>2, ak = (tx&3)<<2;
  const int bk = tx>>4, bn = (tx&15)<<2;
  const int mm = (tx>>4)<<2, nc = (tx&15)<<2;
  for (int kb=0; kb<K; kb+=16){
    float4 av = *reinterpret_cast<const float4*>(A + (size_t)(m0+am)*lda + kb + ak);
    As_[ak][am]=av.x; As_[ak+1][am]=av.y; As_[ak+2][am]=av.z; As_[ak+3][am]=av.w;
    *reinterpret_cast<float4*>(&Bs_[bk][bn]) =
      *reinterpret_cast<const float4*>(B + (size_t)(kb+bk)*ldb + n0 + bn);
    __syncthreads();
    #pragma unroll
    for (int k=0;k<16;k++){
      float4 a4 = *reinterpret_cast<const float4*>(&As_[k][mm]);
      float4 b4 = *reinterpret_cast<const float4*>(&Bs_[k][nc]);
      acc[0][0]=fmaf(a4.x,b4.x,acc[0][0]); acc[0][1]=fmaf(a4.x,b4.y,acc[0][1]);
      acc[0][2]=fmaf(a4.x,b4.z,acc[0][2]); acc[0][3]=fmaf(a4.x,b4.w,acc[0][3]);
      acc[1][0]=fmaf(a4.y,b4.x,acc[1][0]); acc[1][1]=fmaf(a4.y,b4.y,acc[1][1]);
      acc[1][2]=fmaf(a4.y,b4.z,acc[1][2]); acc[1][3]=fmaf(a4.y,b4.w,acc[1][3]);
      acc[2][0]=fmaf(a4.z,b4.x,acc[2][0]); acc[2][1]=fmaf(a4.z,b4.y,acc[2][1]);
      acc[2][2]=fmaf(a4.z,b4.z,acc[2][2]); acc[2][3]=fmaf(a4.z,b4.w,acc[2][3]);
      acc[3][0]=fmaf(a4.w,b4.x,acc[3][0]); acc[3][1]=fmaf(a4.w,b4.y,acc[3][1]);
      acc[3][2]=fmaf(a4.w,b4.z,acc[3][2]); acc[3][3]=fmaf(a4.w,b4.w,acc[3][3]);
    }
    __syncthreads();
  }
  #pragma unroll
  for (int r=0;r<4;r++){
    float4 v = make_float4(acc[r][0],acc[r][1],acc[r][2],acc[r][3]);
    if (relu){ v.x=fmaxf(v.x,0.f); v.y=fmaxf(v.y,0.f); v.z=fmaxf(v.z,0.f); v.w=fmaxf(v.w,0.f); }
    *reinterpret_cast<float4*>(C + (size_t)(m0+mm+r)*ldc + n0 + nc) = v;
  }
}

__global__ __launch_bounds__(256) void gemm_nt(
    float* __restrict__ C, const float* __restrict__ A, const float* __restrict__ B,
    int K, int lda, int ldb, int ldc)
{
  __shared__ float As_[16][68];
  __shared__ float Bs_[16][68];
  float acc[4][4] = {};
  const int tx = threadIdx.x;
  const int m0 = blockIdx.y<<6, n0 = blockIdx.x<<6;
  const int am = tx>>2, ak = (tx&3)<<2;
  const int mm = (tx>>4)<<2, nc = (tx&15)<<2;
  for (int kb=0; kb<K; kb+=16){
    float4 av = *reinterpret_cast<const float4*>(A + (size_t)(m0+am)*lda + kb + ak);
    As_[ak][am]=av.x; As_[ak+1][am]=av.y; As_[ak+2][am]=av.z; As_[ak+3][am]=av.w;
    float4 bv = *reinterpret_cast<const float4*>(B + (size_t)(n0+am)*ldb + kb + ak);
    Bs_[ak][am]=bv.x; Bs_[ak+1][am]=bv.y; Bs_[ak+2][am]=bv.z; Bs_[ak+3][am]=bv.w;
    __syncthreads();
    #pragma unroll
    for (int k=0;k<16;k++){
      float4 a4 = *reinterpret_cast<const float4*>(&As_[k][mm]);
      float4 b4 = *reinterpret_cast<const float4*>(&Bs_[k][nc]);
      acc[0][0]=fmaf(a4.x,b4.x,acc[0][0]); acc[0][1]=fmaf(a4.x,b4.y,acc[0][1]);
      acc[0][2]=fmaf(a4.x,b4.z,acc[0][2]); acc[0][3]=fmaf(a4.x,b4.w,acc[0][3]);
      acc[1][0]=fmaf(a4.y,b4.x,acc[1][0]); acc[1][1]=fmaf(a4.y,b4.y,acc[1][1]);
      acc[1][2]=fmaf(a4.y,b4.z,acc[1][2]); acc[1][3]=fmaf(a4.y,b4.w,acc[1][3]);
      acc[2][0]=fmaf(a4.z,b4.x,acc[2][0]); acc[2][1]=fmaf(a4.z,b4.y,acc[2][1]);
      acc[2][2]=fmaf(a4.z,b4.z,acc[2][2]); acc[2][3]=fmaf(a4.z,b4.w,acc[2][3]);
      acc[3][0]=fmaf(a4.w,b4.x,acc[3][0]); acc[3][1]=fmaf(a4.w,b4.y,acc[3][1]);
      acc[3][2]=fmaf(a4.w,b4.z,acc[3][2]); acc[3][3]=fmaf(a4.w,b4.w,acc[3][3]);
    }
    __syncthreads();
  }
  #pragma unroll
  for (int r=0;r<4;r++){
    float4 v = make_float4(acc[r][0],acc[r][1],acc[r][2],acc[r][3]);
    *reinterpret_cast<float4*>(C + (size_t)(m0+mm+r)*ldc + n0 + nc) = v;
  }
}

__global__ __launch_bounds__(256) void rowstat(const float* __restrict__ nf,
    float* __restrict__ xc, float* __restrict__ dvec)
{
  __shared__ float red[256];
  int n = blockIdx.x, tx = threadIdx.x;
  float v = nf[(size_t)n*HH + tx];
  red[tx] = v; __syncthreads();
  for (int s=128; s>0; s>>=1){ if (tx<s) red[tx]+=red[tx+s]; __syncthreads(); }
  float mean = red[0] * (1.0f/HH);
  __syncthreads();
  float d = v - mean;
  xc[(size_t)n*HH + tx] = d;
  red[tx] = d*d; __syncthreads();
  for (int s=128; s>0; s>>=1){ if (tx<s) red[tx]+=red[tx+s]; __syncthreads(); }
  if (tx==0) dvec[n] = sqrtf(red[0]);
}

__global__ __launch_bounds__(256) void rowsum(const float* __restrict__ cov,
    const float* __restrict__ dvec, float* __restrict__ dinv)
{
  __shared__ float red[256];
  int i = blockIdx.x, tx = threadIdx.x;
  float di = dvec[i];
  float s = 0.f;
  for (int jj=tx; jj<NN; jj+=256){
    float r = cov[(size_t)i*NN + jj] / (di * dvec[jj]);
    if (r != r) r = 0.f; else r = fminf(1.f, fmaxf(-1.f, r));
    s += r;
  }
  red[tx]=s; __syncthreads();
  for (int st=128; st>0; st>>=1){ if (tx<st) red[tx]+=red[tx+st]; __syncthreads(); }
  if (tx==0){
    float tot = red[0] + 1.0f;
    float p = powf(tot, -0.5f);
    if (isinf(p)) p = 0.f;
    dinv[i] = p;
  }
}

__global__ __launch_bounds__(256) void adjnorm(float* __restrict__ cov,
    const float* __restrict__ dvec, const float* __restrict__ dinv)
{
  size_t idx = (size_t)blockIdx.x*256 + threadIdx.x;
  int i = (int)(idx >> 11), jj = (int)(idx & (NN-1));
  float r = cov[idx] / (dvec[i]*dvec[jj]);
  if (r != r) r = 0.f; else r = fminf(1.f, fmaxf(-1.f, r));
  if (i==jj) r += 1.f;
  cov[idx] = dinv[i]*r*dinv[jj];
}

__global__ __launch_bounds__(128) void predk(const float* __restrict__ G2,
    const float* __restrict__ Wfc, const float* __restrict__ bfc, float* __restrict__ out)
{
  int n = blockIdx.x, tx = threadIdx.x;
  float v = G2[(size_t)n*128 + tx] * Wfc[tx];
  for (int off=32; off>0; off>>=1) v += __shfl_down(v, off);
  __shared__ float p[2];
  if ((tx&63)==0) p[tx>>6] = v;
  __syncthreads();
  if (tx==0) out[n] = p[0] + p[1] + bfc[0];
}

extern "C" void kernel_launch(void* const* d_in, const int* in_sizes, int n_in,
                              void* d_out, int out_size, void* d_ws, size_t ws_size,
                              hipStream_t stream)
{
  const float* x    = (const float*)d_in[0];
  const float* Wih0 = (const float*)d_in[1];
  const float* Whh0 = (const float*)d_in[2];
  const float* bih0 = (const float*)d_in[3];
  const float* bhh0 = (const float*)d_in[4];
  const float* Wih1 = (const float*)d_in[5];
  const float* Whh1 = (const float*)d_in[6];
  const float* bih1 = (const float*)d_in[7];
  const float* bhh1 = (const float*)d_in[8];
  const float* Wg1  = (const float*)d_in[9];
  const float* Wg2  = (const float*)d_in[10];
  const float* Wfc  = (const float*)d_in[11];
  const float* bfc  = (const float*)d_in[12];
  float* out = (float*)d_out;

  char* w = (char*)d_ws;
  auto alloc = [&](size_t bytes){ char* p = w; w += (bytes + 255) & ~(size_t)255; return p; };
  __hip_bfloat16* Xp   = (__hip_bfloat16*)alloc((size_t)NN*TT*64*2);
  __hip_bfloat16* P0hh = (__hip_bfloat16*)alloc((size_t)1024*512*2);
  __hip_bfloat16* P1ih = (__hip_bfloat16*)alloc((size_t)1024*512*2);
  __hip_bfloat16* P1hh = (__hip_bfloat16*)alloc((size_t)1024*512*2);
  __hip_bfloat16* P0ih = (__hip_bfloat16*)alloc((size_t)1024*64*2);
  __hip_bfloat16 *H0hi[2], *H0lo[2], *H1hi[2], *H1lo[2];
  for (int i=0;i<2;i++){ H0hi[i]=(__hip_bfloat16*)alloc((size_t)NN*HH*2);
                         H0lo[i]=(__hip_bfloat16*)alloc((size_t)NN*HH*2); }
  for (int i=0;i<2;i++){ H1hi[i]=(__hip_bfloat16*)alloc((size_t)NN*HH*2);
                         H1lo[i]=(__hip_bfloat16*)alloc((size_t)NN*HH*2); }
  float* c0   = (float*)alloc((size_t)NN*HH*4);
  float* c1   = (float*)alloc((size_t)NN*HH*4);
  float* nf   = (float*)alloc((size_t)NN*HH*4);
  float* xc   = (float*)alloc((size_t)NN*HH*4);
  float* cov  = (float*)alloc((size_t)NN*NN*4);
  float* t1   = (float*)alloc((size_t)NN*HH*4);
  float* G1   = (float*)alloc((size_t)NN*HH*4);
  float* t2   = (float*)alloc((size_t)NN*128*4);
  float* G2   = (float*)alloc((size_t)NN*128*4);
  float* dvec = (float*)alloc((size_t)NN*4);
  float* dinv = (float*)alloc((size_t)NN*4);

  hipLaunchKernelGGL(pack_w2, dim3(1024), dim3(256), 0, stream, Whh0, P0hh);
  hipLaunchKernelGGL(pack_w2, dim3(1024), dim3(256), 0, stream, Wih1, P1ih);
  hipLaunchKernelGGL(pack_w2, dim3(1024), dim3(256), 0, stream, Whh1, P1hh);
  hipLaunchKernelGGL(pack_w0, dim3(64),   dim3(256), 0, stream, Wih0, P0ih);
  hipLaunchKernelGGL(pack_x,  dim3(2048), dim3(256), 0, stream, x, Xp);

  // skewed recurrence: launch t runs L0(t) and L1(t-1)
  for (int t=0; t<=TT; ++t){
    const __hip_bfloat16 *h0p_hi = H0hi[(t+1)&1], *h0p_lo = H0lo[(t+1)&1];
    __hip_bfloat16 *h0o_hi = H0hi[t&1], *h0o_lo = H0lo[t&1];
    const __hip_bfloat16 *h1p_hi = H1hi[t&1], *h1p_lo = H1lo[t&1];
    __hip_bfloat16 *h1o_hi = H1hi[(t+1)&1], *h1o_lo = H1lo[(t+1)&1];
    hipLaunchKernelGGL(lstm2_step, dim3(512), dim3(256), 0, stream,
        t, Xp, P0ih, P0hh, P1ih, P1hh, bih0, bhh0, bih1, bhh1,
        h0p_hi, h0p_lo, h0o_hi, h0o_lo, h1p_hi, h1p_lo, h1o_hi, h1o_lo, c0, c1);
  }
  // final h1 (step 255, written at launch t=256) lives in H1[1]
  hipLaunchKernelGGL(recon_nf, dim3(2048), dim3(256), 0, stream, H1hi[1], H1lo[1], nf);

  hipLaunchKernelGGL(rowstat, dim3(NN), dim3(256), 0, stream, nf, xc, dvec);
  hipLaunchKernelGGL(gemm_nt, dim3(NN/64, NN/64), dim3(256), 0, stream,
      cov, xc, xc, HH, HH, HH, NN);
  hipLaunchKernelGGL(rowsum, dim3(NN), dim3(256), 0, stream, cov, dvec, dinv);
  hipLaunchKernelGGL(adjnorm, dim3(NN*NN/256), dim3(256), 0, stream, cov, dvec, dinv);

  hipLaunchKernelGGL(gemm_nn, dim3(HH/64, NN/64), dim3(256), 0, stream,
      t1, nf, Wg1, HH, HH, HH, HH, 0);
  hipLaunchKernelGGL(gemm_nn, dim3(HH/64, NN/64), dim3(256), 0, stream,
      G1, cov, t1, NN, NN, HH, HH, 1);
  hipLaunchKernelGGL(gemm_nn, dim3(128/64, NN/64), dim3(256), 0, stream,
      t2, G1, Wg2, HH, HH, 128, 128, 0);
  hipLaunchKernelGGL(gemm_nn, dim3(128/64, NN/64), dim3(256), 0, stream,
      G2, cov, t2, NN, NN, 128, 128, 0);
  hipLaunchKernelGGL(predk, dim3(NN), dim3(128), 0, stream, G2, Wfc, bfc, out);
}

// Round 4
// 4761.326 us; speedup vs baseline: 5.3831x; 1.3362x over previous
//
#include <hip/hip_runtime.h>
#include <hip/hip_bf16.h>
#include <cmath>

#define NN 2048
#define TT 256
#define DD 16
#define HH 256

typedef __attribute__((ext_vector_type(8))) short short8;
typedef __attribute__((ext_vector_type(4))) float f32x4;

__device__ __forceinline__ float sigmoidf_(float x){ return 1.0f/(1.0f+expf(-x)); }

// async 16B/lane global->LDS (LDS dest wave-uniform base; HW adds lane*16)
__device__ __forceinline__ void glds16(const __hip_bfloat16* g, __hip_bfloat16* l){
  __builtin_amdgcn_global_load_lds(
      (const __attribute__((address_space(1))) void*)g,
      (__attribute__((address_space(3))) void*)l, 16, 0, 0);
}

// ---------------- packing ----------------
// W (1024x256) -> P (1024x512): [hi | lo]
__global__ __launch_bounds__(256) void pack_w2(const float* __restrict__ W,
                                               __hip_bfloat16* __restrict__ P){
  int tid = blockIdx.x*256 + threadIdx.x;   // 1024 blocks
  int r = tid >> 8, k = tid & 255;
  float w = W[tid];
  __hip_bfloat16 h = __float2bfloat16(w);
  __hip_bfloat16 l = __float2bfloat16(w - __bfloat162float(h));
  size_t base = (size_t)r*512;
  P[base + k] = h; P[base + 256 + k] = l;
}
// Wih0 (1024 x 16) -> (1024 x 64): [hi | hi | lo | 0] (pairs with x [hi|lo|hi|0])
__global__ __launch_bounds__(256) void pack_w0(const float* __restrict__ W,
                                               __hip_bfloat16* __restrict__ P){
  int tid = blockIdx.x*256 + threadIdx.x;   // 64 blocks
  int r = tid >> 4, k = tid & 15;
  float w = W[tid];
  __hip_bfloat16 h = __float2bfloat16(w);
  __hip_bfloat16 l = __float2bfloat16(w - __bfloat162float(h));
  size_t base = (size_t)r*64;
  P[base + k] = h; P[base + 16 + k] = h; P[base + 32 + k] = l;
  P[base + 48 + k] = __float2bfloat16(0.0f);
}
// x (N,T,16) -> Xp (N,T,64): [hi | lo | hi | 0]
__global__ __launch_bounds__(256) void pack_x(const float* __restrict__ x,
                                              __hip_bfloat16* __restrict__ Xp){
  int tid = blockIdx.x*256 + threadIdx.x;   // 2048 blocks
  const float* xr = x + (size_t)tid*16;
  __hip_bfloat16* o = Xp + (size_t)tid*64;
  for (int k=0;k<16;k++){
    float v = xr[k];
    __hip_bfloat16 h = __float2bfloat16(v);
    __hip_bfloat16 l = __float2bfloat16(v - __bfloat162float(h));
    o[k] = h; o[16+k] = l; o[32+k] = h; o[48+k] = __float2bfloat16(0.0f);
  }
}
__global__ __launch_bounds__(256) void recon_nf(const __hip_bfloat16* __restrict__ hi,
    const __hip_bfloat16* __restrict__ lo, float* __restrict__ nf){
  int tid = blockIdx.x*256 + threadIdx.x;
  nf[tid] = __bfloat162float(hi[tid]) + __bfloat162float(lo[tid]);
}

// ---------------- GEMM segment: merged-A chunks, drain pattern ----------------
// Block tile: 128 m x 16 j x 4 gates. 4 waves; wave stages its 32 m-rows of
// A-hi AND A-lo plus gate-group wv's 16 rows of B-hi and B-lo per k64 chunk.
// Per chunk: stage(12 glds16) -> sync (drains) -> 3-pass MFMA (hi*Bhi, lo*Bhi,
// hi*Blo) -> sync. No load outstanding across a barrier->MFMA boundary.
__device__ __forceinline__ void mm_merged(
    const __hip_bfloat16* __restrict__ Ahi, const __hip_bfloat16* __restrict__ Alo,
    size_t lda,
    const __hip_bfloat16* __restrict__ Bhi, const __hip_bfloat16* __restrict__ Blo,
    size_t ldb, int Klen,
    int m0, int j0, int wv, int lane, int rr, int sw8, int frow,
    f32x4 (&acc)[2][4],
    __hip_bfloat16* AsH, __hip_bfloat16* AsL,
    __hip_bfloat16* BsH, __hip_bfloat16* BsL)
{
  const size_t arow = (size_t)(m0 + wv*32 + rr)*lda + sw8;
  const size_t brow = (size_t)(wv*256 + j0 + rr)*ldb + sw8;
  for (int kb=0; kb<Klen; kb+=64){
    {
      const __hip_bfloat16* AbH = Ahi + arow + kb;
      __hip_bfloat16* AdH = AsH + (wv*32)*64;
      #pragma unroll
      for (int c2=0;c2<4;c2++) glds16(AbH + (size_t)(c2*8)*lda, AdH + c2*8*64);
      const __hip_bfloat16* AbL = Alo + arow + kb;
      __hip_bfloat16* AdL = AsL + (wv*32)*64;
      #pragma unroll
      for (int c2=0;c2<4;c2++) glds16(AbL + (size_t)(c2*8)*lda, AdL + c2*8*64);
      const __hip_bfloat16* Bb1 = Bhi + brow + kb;
      __hip_bfloat16* Bd1 = BsH + (wv<<4)*64;
      glds16(Bb1, Bd1); glds16(Bb1 + (size_t)8*ldb, Bd1 + 8*64);
      const __hip_bfloat16* Bb2 = Blo + brow + kb;
      __hip_bfloat16* Bd2 = BsL + (wv<<4)*64;
      glds16(Bb2, Bd2); glds16(Bb2 + (size_t)8*ldb, Bd2 + 8*64);
    }
    __syncthreads();          // drains this chunk's loads
    #pragma unroll
    for (int w2=0; w2<2; ++w2){
      const int sl8 = ((((w2<<2) + (lane>>4)) ^ (lane&7)) << 3);
      short8 ah0 = *(const short8*)&AsH[(wv*32 +      frow)*64 + sl8];
      short8 ah1 = *(const short8*)&AsH[(wv*32 + 16 + frow)*64 + sl8];
      short8 al0 = *(const short8*)&AsL[(wv*32 +      frow)*64 + sl8];
      short8 al1 = *(const short8*)&AsL[(wv*32 + 16 + frow)*64 + sl8];
      #pragma unroll
      for (int g=0; g<4; ++g){
        short8 bh = *(const short8*)&BsH[((g<<4) + frow)*64 + sl8];
        acc[0][g] = __builtin_amdgcn_mfma_f32_16x16x32_bf16(ah0, bh, acc[0][g], 0,0,0);
        acc[1][g] = __builtin_amdgcn_mfma_f32_16x16x32_bf16(ah1, bh, acc[1][g], 0,0,0);
        acc[0][g] = __builtin_amdgcn_mfma_f32_16x16x32_bf16(al0, bh, acc[0][g], 0,0,0);
        acc[1][g] = __builtin_amdgcn_mfma_f32_16x16x32_bf16(al1, bh, acc[1][g], 0,0,0);
        short8 bl = *(const short8*)&BsL[((g<<4) + frow)*64 + sl8];
        acc[0][g] = __builtin_amdgcn_mfma_f32_16x16x32_bf16(ah0, bl, acc[0][g], 0,0,0);
        acc[1][g] = __builtin_amdgcn_mfma_f32_16x16x32_bf16(ah1, bl, acc[1][g], 0,0,0);
      }
    }
    __syncthreads();
  }
}

// single-B, one 64-panel (for the K=64 x-chunk) — exact R8 shape
__device__ __forceinline__ void mm_single64(
    const __hip_bfloat16* __restrict__ A, size_t lda,
    const __hip_bfloat16* __restrict__ B, size_t ldb,
    int m0, int j0, int wv, int lane, int rr, int sw8, int frow,
    f32x4 (&acc)[2][4],
    __hip_bfloat16* As0, __hip_bfloat16* Bh0)
{
  {
    const __hip_bfloat16* Ab = A + (size_t)(m0 + wv*32 + rr)*lda + sw8;
    __hip_bfloat16* Ad = As0 + (wv*32)*64;
    #pragma unroll
    for (int c2=0;c2<4;c2++) glds16(Ab + (size_t)(c2*8)*lda, Ad + c2*8*64);
    const __hip_bfloat16* Bb1 = B + (size_t)(wv*256 + j0 + rr)*ldb + sw8;
    __hip_bfloat16* Bd1 = Bh0 + (wv<<4)*64;
    glds16(Bb1, Bd1); glds16(Bb1 + (size_t)8*ldb, Bd1 + 8*64);
  }
  __syncthreads();
  #pragma unroll
  for (int w2=0; w2<2; ++w2){
    const int sl8 = ((((w2<<2) + (lane>>4)) ^ (lane&7)) << 3);
    short8 a0 = *(const short8*)&As0[(wv*32 +      frow)*64 + sl8];
    short8 a1 = *(const short8*)&As0[(wv*32 + 16 + frow)*64 + sl8];
    #pragma unroll
    for (int g=0; g<4; ++g){
      short8 b1 = *(const short8*)&Bh0[((g<<4) + frow)*64 + sl8];
      acc[0][g] = __builtin_amdgcn_mfma_f32_16x16x32_bf16(a0, b1, acc[0][g], 0,0,0);
      acc[1][g] = __builtin_amdgcn_mfma_f32_16x16x32_bf16(a1, b1, acc[1][g], 0,0,0);
    }
  }
  __syncthreads();
}

// ---------------- fused two-layer skewed LSTM step (MFMA bf16x3) ----------------
// XCD-aware mapping (round-robin bid->XCD assumed, perf-only): XCDs 0-3 run
// layer0, XCDs 4-7 run layer1. Within a layer's 4 XCDs, each XCD owns an
// (8 mg x 8 jg) quadrant so its L2 working set (weight j-slice + h m-slice)
// fits in 4 MB: L0 ~2 MB, L1 ~4 MB. Pure relabeling; per-block math unchanged.
__global__ __launch_bounds__(256, 2) void lstm2_step(
    int t,
    const __hip_bfloat16* __restrict__ Xp,
    const __hip_bfloat16* __restrict__ P0ih,
    const __hip_bfloat16* __restrict__ P0hh,
    const __hip_bfloat16* __restrict__ P1ih,
    const __hip_bfloat16* __restrict__ P1hh,
    const float* __restrict__ bih0, const float* __restrict__ bhh0,
    const float* __restrict__ bih1, const float* __restrict__ bhh1,
    const __hip_bfloat16* __restrict__ h0p_hi, const __hip_bfloat16* __restrict__ h0p_lo,
    __hip_bfloat16* __restrict__ h0o_hi, __hip_bfloat16* __restrict__ h0o_lo,
    const __hip_bfloat16* __restrict__ h1p_hi, const __hip_bfloat16* __restrict__ h1p_lo,
    __hip_bfloat16* __restrict__ h1o_hi, __hip_bfloat16* __restrict__ h1o_lo,
    float* __restrict__ c0, float* __restrict__ c1)
{
  __shared__ __align__(16) __hip_bfloat16 AsH[128*64];   // 16 KB
  __shared__ __align__(16) __hip_bfloat16 AsL[128*64];   // 16 KB
  __shared__ __align__(16) __hip_bfloat16 BsH[64*64];    // 8 KB
  __shared__ __align__(16) __hip_bfloat16 BsL[64*64];    // 8 KB

  const int bid = blockIdx.x;
  const int xcd = bid & 7;            // presumed XCD (round-robin dispatch)
  const int slot = bid >> 3;          // 0..63 within this XCD
  const bool isL0 = xcd < 4;
  if (isL0 && t >= TT) return;
  if (!isL0 && t == 0) return;
  const int lg = isL0 ? xcd : (xcd - 4);          // 2-bit quadrant id
  const int jg = ((lg & 1) << 3) + (slot & 7);    // 0..15
  const int mg = ((lg >> 1) << 3) + (slot >> 3);  // 0..15
  const int m0 = mg << 7;
  const int j0 = jg << 4;
  const int lane = threadIdx.x & 63, wv = threadIdx.x >> 6;
  const int rr = lane >> 3;
  const int sw8 = (((lane & 7) ^ rr) << 3);     // source-side XOR swizzle
  const int frow = lane & 15;

  f32x4 acc[2][4] = {};                 // [m-subtile][gate]

  if (isL0){
    if (t != 0){
      mm_merged(h0p_hi, h0p_lo, 256, P0hh, P0hh+256, 512, 256,
                m0, j0, wv, lane, rr, sw8, frow, acc, AsH, AsL, BsH, BsL);
    }
    mm_single64(Xp + (size_t)t*64, (size_t)TT*64, P0ih, 64,
                m0, j0, wv, lane, rr, sw8, frow, acc, AsH, BsH);
  } else {
    mm_merged(h0p_hi, h0p_lo, 256, P1ih, P1ih+256, 512, 256,
              m0, j0, wv, lane, rr, sw8, frow, acc, AsH, AsL, BsH, BsL);
    if (t != 1){
      mm_merged(h1p_hi, h1p_lo, 256, P1hh, P1hh+256, 512, 256,
                m0, j0, wv, lane, rr, sw8, frow, acc, AsH, AsL, BsH, BsL);
    }
  }

  // epilogue: lane holds all 4 gates. C map: col=lane&15, row=(lane>>4)*4+r
  const int j = j0 + frow;
  const float* bih = isL0 ? bih0 : bih1;
  const float* bhh = isL0 ? bhh0 : bhh1;
  float* cst = isL0 ? c0 : c1;
  __hip_bfloat16* ohi = isL0 ? h0o_hi : h1o_hi;
  __hip_bfloat16* olo = isL0 ? h0o_lo : h1o_lo;
  const int first = isL0 ? (t==0) : (t==1);
  const float b0 = bih[j]        + bhh[j];
  const float b1 = bih[HH + j]   + bhh[HH + j];
  const float b2 = bih[2*HH + j] + bhh[2*HH + j];
  const float b3 = bih[3*HH + j] + bhh[3*HH + j];
  #pragma unroll
  for (int mt=0; mt<2; ++mt){
    const int mrb = m0 + wv*32 + mt*16 + ((lane>>4)<<2);
    #pragma unroll
    for (int r=0; r<4; ++r){
      const size_t mi = (size_t)(mrb + r)*HH + j;
      float gi = acc[mt][0][r] + b0;
      float gf = acc[mt][1][r] + b1;
      float gg = acc[mt][2][r] + b2;
      float go = acc[mt][3][r] + b3;
      float cold = first ? 0.f : cst[mi];
      float cn = sigmoidf_(gf)*cold + sigmoidf_(gi)*tanhf(gg);
      float hv = sigmoidf_(go)*tanhf(cn);
      cst[mi] = cn;
      __hip_bfloat16 hb = __float2bfloat16(hv);
      ohi[mi] = hb;
      olo[mi] = __float2bfloat16(hv - __bfloat162float(hb));
    }
  }
}

// ---------------- fp32 tail (unchanged, proven) ----------------
__global__ __launch_bounds__(256) void gemm_nn(
    float* __restrict__ C, const float* __restrict__ A, const float* __restrict__ B,
    int K, int lda, int ldb, int ldc, int relu)
{
  __shared__ float As_[16][68];
  __shared__ float Bs_[16][64];
  float acc[4][4] = {};
  const int tx = threadIdx.x;
  const int m0 = blockIdx.y<<6, n0 = blockIdx.x<<6;
  const int am = tx>>2, ak = (tx&3)<<2;
  const int bk = tx>>4, bn = (tx&15)<<2;
  const int mm = (tx>>4)<<2, nc = (tx&15)<<2;
  for (int kb=0; kb<K; kb+=16){
    float4 av = *reinterpret_cast<const float4*>(A + (size_t)(m0+am)*lda + kb + ak);
    As_[ak][am]=av.x; As_[ak+1][am]=av.y; As_[ak+2][am]=av.z; As_[ak+3][am]=av.w;
    *reinterpret_cast<float4*>(&Bs_[bk][bn]) =
      *reinterpret_cast<const float4*>(B + (size_t)(kb+bk)*ldb + n0 + bn);
    __syncthreads();
    #pragma unroll
    for (int k=0;k<16;k++){
      float4 a4 = *reinterpret_cast<const float4*>(&As_[k][mm]);
      float4 b4 = *reinterpret_cast<const float4*>(&Bs_[k][nc]);
      acc[0][0]=fmaf(a4.x,b4.x,acc[0][0]); acc[0][1]=fmaf(a4.x,b4.y,acc[0][1]);
      acc[0][2]=fmaf(a4.x,b4.z,acc[0][2]); acc[0][3]=fmaf(a4.x,b4.w,acc[0][3]);
      acc[1][0]=fmaf(a4.y,b4.x,acc[1][0]); acc[1][1]=fmaf(a4.y,b4.y,acc[1][1]);
      acc[1][2]=fmaf(a4.y,b4.z,acc[1][2]); acc[1][3]=fmaf(a4.y,b4.w,acc[1][3]);
      acc[2][0]=fmaf(a4.z,b4.x,acc[2][0]); acc[2][1]=fmaf(a4.z,b4.y,acc[2][1]);
      acc[2][2]=fmaf(a4.z,b4.z,acc[2][2]); acc[2][3]=fmaf(a4.z,b4.w,acc[2][3]);
      acc[3][0]=fmaf(a4.w,b4.x,acc[3][0]); acc[3][1]=fmaf(a4.w,b4.y,acc[3][1]);
      acc[3][2]=fmaf(a4.w,b4.z,acc[3][2]); acc[3][3]=fmaf(a4.w,b4.w,acc[3][3]);
    }
    __syncthreads();
  }
  #pragma unroll
  for (int r=0;r<4;r++){
    float4 v = make_float4(acc[r][0],acc[r][1],acc[r][2],acc[r][3]);
    if (relu){ v.x=fmaxf(v.x,0.f); v.y=fmaxf(v.y,0.f); v.z=fmaxf(v.z,0.f); v.w=fmaxf(v.w,0.f); }
    *reinterpret_cast<float4*>(C + (size_t)(m0+mm+r)*ldc + n0 + nc) = v;
  }
}

__global__ __launch_bounds__(256) void gemm_nt(
    float* __restrict__ C, const float* __restrict__ A, const float* __restrict__ B,
    int K, int lda, int ldb, int ldc)
{
  __shared__ float As_[16][68];
  __shared__ float Bs_[16][68];
  float acc[4][4] = {};
  const int tx = threadIdx.x;
  const int m0 = blockIdx.y<<6, n0 = blockIdx.x<<6;
  const int am = tx>>2, ak = (tx&3)<<2;
  const int mm = (tx>>4)<<2, nc = (tx&15)<<2;
  for (int kb=0; kb<K; kb+=16){
    float4 av = *reinterpret_cast<const float4*>(A + (size_t)(m0+am)*lda + kb + ak);
    As_[ak][am]=av.x; As_[ak+1][am]=av.y; As_[ak+2][am]=av.z; As_[ak+3][am]=av.w;
    float4 bv = *reinterpret_cast<const float4*>(B + (size_t)(n0+am)*ldb + kb + ak);
    Bs_[ak][am]=bv.x; Bs_[ak+1][am]=bv.y; Bs_[ak+2][am]=bv.z; Bs_[ak+3][am]=bv.w;
    __syncthreads();
    #pragma unroll
    for (int k=0;k<16;k++){
      float4 a4 = *reinterpret_cast<const float4*>(&As_[k][mm]);
      float4 b4 = *reinterpret_cast<const float4*>(&Bs_[k][nc]);
      acc[0][0]=fmaf(a4.x,b4.x,acc[0][0]); acc[0][1]=fmaf(a4.x,b4.y,acc[0][1]);
      acc[0][2]=fmaf(a4.x,b4.z,acc[0][2]); acc[0][3]=fmaf(a4.x,b4.w,acc[0][3]);
      acc[1][0]=fmaf(a4.y,b4.x,acc[1][0]); acc[1][1]=fmaf(a4.y,b4.y,acc[1][1]);
      acc[1][2]=fmaf(a4.y,b4.z,acc[1][2]); acc[1][3]=fmaf(a4.y,b4.w,acc[1][3]);
      acc[2][0]=fmaf(a4.z,b4.x,acc[2][0]); acc[2][1]=fmaf(a4.z,b4.y,acc[2][1]);
      acc[2][2]=fmaf(a4.z,b4.z,acc[2][2]); acc[2][3]=fmaf(a4.z,b4.w,acc[2][3]);
      acc[3][0]=fmaf(a4.w,b4.x,acc[3][0]); acc[3][1]=fmaf(a4.w,b4.y,acc[3][1]);
      acc[3][2]=fmaf(a4.w,b4.z,acc[3][2]); acc[3][3]=fmaf(a4.w,b4.w,acc[3][3]);
    }
    __syncthreads();
  }
  #pragma unroll
  for (int r=0;r<4;r++){
    float4 v = make_float4(acc[r][0],acc[r][1],acc[r][2],acc[r][3]);
    *reinterpret_cast<float4*>(C + (size_t)(m0+mm+r)*ldc + n0 + nc) = v;
  }
}

__global__ __launch_bounds__(256) void rowstat(const float* __restrict__ nf,
    float* __restrict__ xc, float* __restrict__ dvec)
{
  __shared__ float red[256];
  int n = blockIdx.x, tx = threadIdx.x;
  float v = nf[(size_t)n*HH + tx];
  red[tx] = v; __syncthreads();
  for (int s=128; s>0; s>>=1){ if (tx<s) red[tx]+=red[tx+s]; __syncthreads(); }
  float mean = red[0] * (1.0f/HH);
  __syncthreads();
  float d = v - mean;
  xc[(size_t)n*HH + tx] = d;
  red[tx] = d*d; __syncthreads();
  for (int s=128; s>0; s>>=1){ if (tx<s) red[tx]+=red[tx+s]; __syncthreads(); }
  if (tx==0) dvec[n] = sqrtf(red[0]);
}

__global__ __launch_bounds__(256) void rowsum(const float* __restrict__ cov,
    const float* __restrict__ dvec, float* __restrict__ dinv)
{
  __shared__ float red[256];
  int i = blockIdx.x, tx = threadIdx.x;
  float di = dvec[i];
  float s = 0.f;
  for (int jj=tx; jj<NN; jj+=256){
    float r = cov[(size_t)i*NN + jj] / (di * dvec[jj]);
    if (r != r) r = 0.f; else r = fminf(1.f, fmaxf(-1.f, r));
    s += r;
  }
  red[tx]=s; __syncthreads();
  for (int st=128; st>0; st>>=1){ if (tx<st) red[tx]+=red[tx+st]; __syncthreads(); }
  if (tx==0){
    float tot = red[0] + 1.0f;
    float p = powf(tot, -0.5f);
    if (isinf(p)) p = 0.f;
    dinv[i] = p;
  }
}

__global__ __launch_bounds__(256) void adjnorm(float* __restrict__ cov,
    const float* __restrict__ dvec, const float* __restrict__ dinv)
{
  size_t idx = (size_t)blockIdx.x*256 + threadIdx.x;
  int i = (int)(idx >> 11), jj = (int)(idx & (NN-1));
  float r = cov[idx] / (dvec[i]*dvec[jj]);
  if (r != r) r = 0.f; else r = fminf(1.f, fmaxf(-1.f, r));
  if (i==jj) r += 1.f;
  cov[idx] = dinv[i]*r*dinv[jj];
}

__global__ __launch_bounds__(128) void predk(const float* __restrict__ G2,
    const float* __restrict__ Wfc, const float* __restrict__ bfc, float* __restrict__ out)
{
  int n = blockIdx.x, tx = threadIdx.x;
  float v = G2[(size_t)n*128 + tx] * Wfc[tx];
  for (int off=32; off>0; off>>=1) v += __shfl_down(v, off);
  __shared__ float p[2];
  if ((tx&63)==0) p[tx>>6] = v;
  __syncthreads();
  if (tx==0) out[n] = p[0] + p[1] + bfc[0];
}

extern "C" void kernel_launch(void* const* d_in, const int* in_sizes, int n_in,
                              void* d_out, int out_size, void* d_ws, size_t ws_size,
                              hipStream_t stream)
{
  const float* x    = (const float*)d_in[0];
  const float* Wih0 = (const float*)d_in[1];
  const float* Whh0 = (const float*)d_in[2];
  const float* bih0 = (const float*)d_in[3];
  const float* bhh0 = (const float*)d_in[4];
  const float* Wih1 = (const float*)d_in[5];
  const float* Whh1 = (const float*)d_in[6];
  const float* bih1 = (const float*)d_in[7];
  const float* bhh1 = (const float*)d_in[8];
  const float* Wg1  = (const float*)d_in[9];
  const float* Wg2  = (const float*)d_in[10];
  const float* Wfc  = (const float*)d_in[11];
  const float* bfc  = (const float*)d_in[12];
  float* out = (float*)d_out;

  char* w = (char*)d_ws;
  auto alloc = [&](size_t bytes){ char* p = w; w += (bytes + 255) & ~(size_t)255; return p; };
  __hip_bfloat16* Xp   = (__hip_bfloat16*)alloc((size_t)NN*TT*64*2);
  __hip_bfloat16* P0hh = (__hip_bfloat16*)alloc((size_t)1024*512*2);
  __hip_bfloat16* P1ih = (__hip_bfloat16*)alloc((size_t)1024*512*2);
  __hip_bfloat16* P1hh = (__hip_bfloat16*)alloc((size_t)1024*512*2);
  __hip_bfloat16* P0ih = (__hip_bfloat16*)alloc((size_t)1024*64*2);
  __hip_bfloat16 *H0hi[2], *H0lo[2], *H1hi[2], *H1lo[2];
  for (int i=0;i<2;i++){ H0hi[i]=(__hip_bfloat16*)alloc((size_t)NN*HH*2);
                         H0lo[i]=(__hip_bfloat16*)alloc((size_t)NN*HH*2); }
  for (int i=0;i<2;i++){ H1hi[i]=(__hip_bfloat16*)alloc((size_t)NN*HH*2);
                         H1lo[i]=(__hip_bfloat16*)alloc((size_t)NN*HH*2); }
  float* c0   = (float*)alloc((size_t)NN*HH*4);
  float* c1   = (float*)alloc((size_t)NN*HH*4);
  float* nf   = (float*)alloc((size_t)NN*HH*4);
  float* xc   = (float*)alloc((size_t)NN*HH*4);
  float* cov  = (float*)alloc((size_t)NN*NN*4);
  float* t1   = (float*)alloc((size_t)NN*HH*4);
  float* G1   = (float*)alloc((size_t)NN*HH*4);
  float* t2   = (float*)alloc((size_t)NN*128*4);
  float* G2   = (float*)alloc((size_t)NN*128*4);
  float* dvec = (float*)alloc((size_t)NN*4);
  float* dinv = (float*)alloc((size_t)NN*4);

  hipLaunchKernelGGL(pack_w2, dim3(1024), dim3(256), 0, stream, Whh0, P0hh);
  hipLaunchKernelGGL(pack_w2, dim3(1024), dim3(256), 0, stream, Wih1, P1ih);
  hipLaunchKernelGGL(pack_w2, dim3(1024), dim3(256), 0, stream, Whh1, P1hh);
  hipLaunchKernelGGL(pack_w0, dim3(64),   dim3(256), 0, stream, Wih0, P0ih);
  hipLaunchKernelGGL(pack_x,  dim3(2048), dim3(256), 0, stream, x, Xp);

  // skewed recurrence: launch t runs L0(t) and L1(t-1)
  for (int t=0; t<=TT; ++t){
    const __hip_bfloat16 *h0p_hi = H0hi[(t+1)&1], *h0p_lo = H0lo[(t+1)&1];
    __hip_bfloat16 *h0o_hi = H0hi[t&1], *h0o_lo = H0lo[t&1];
    const __hip_bfloat16 *h1p_hi = H1hi[t&1], *h1p_lo = H1lo[t&1];
    __hip_bfloat16 *h1o_hi = H1hi[(t+1)&1], *h1o_lo = H1lo[(t+1)&1];
    hipLaunchKernelGGL(lstm2_step, dim3(512), dim3(256), 0, stream,
        t, Xp, P0ih, P0hh, P1ih, P1hh, bih0, bhh0, bih1, bhh1,
        h0p_hi, h0p_lo, h0o_hi, h0o_lo, h1p_hi, h1p_lo, h1o_hi, h1o_lo, c0, c1);
  }
  // final h1 (step 255, written at launch t=256) lives in H1[1]
  hipLaunchKernelGGL(recon_nf, dim3(2048), dim3(256), 0, stream, H1hi[1], H1lo[1], nf);

  hipLaunchKernelGGL(rowstat, dim3(NN), dim3(256), 0, stream, nf, xc, dvec);
  hipLaunchKernelGGL(gemm_nt, dim3(NN/64, NN/64), dim3(256), 0, stream,
      cov, xc, xc, HH, HH, HH, NN);
  hipLaunchKernelGGL(rowsum, dim3(NN), dim3(256), 0, stream, cov, dvec, dinv);
  hipLaunchKernelGGL(adjnorm, dim3(NN*NN/256), dim3(256), 0, stream, cov, dvec, dinv);

  hipLaunchKernelGGL(gemm_nn, dim3(HH/64, NN/64), dim3(256), 0, stream,
      t1, nf, Wg1, HH, HH, HH, HH, 0);
  hipLaunchKernelGGL(gemm_nn, dim3(HH/64, NN/64), dim3(256), 0, stream,
      G1, cov, t1, NN, NN, HH, HH, 1);
  hipLaunchKernelGGL(gemm_nn, dim3(128/64, NN/64), dim3(256), 0, stream,
      t2, G1, Wg2, HH, HH, 128, 128, 0);
  hipLaunchKernelGGL(gemm_nn, dim3(128/64, NN/64), dim3(256), 0, stream,
      G2, cov, t2, NN, NN, 128, 128, 0);
  hipLaunchKernelGGL(predk, dim3(NN), dim3(128), 0, stream, G2, Wfc, bfc, out);
}